// Round 1
// baseline (2401.398 us; speedup 1.0000x reference)
//
#include <hip/hip_runtime.h>
#include <stdint.h>

#define Bq 32
#define Nq 512
#define Hq 128
#define NHq 8
#define HDq 16
#define Mq (Bq * Nq)   // 16384

// ---------- dtype-flex helpers (flag: 1 = inputs are bf16, 0 = f32) ----------
__device__ __forceinline__ float bf2f(unsigned short v) {
    return __uint_as_float(((unsigned int)v) << 16);
}
__device__ __forceinline__ float ldin(const void* p, long idx, int bf) {
    if (bf) return bf2f(((const unsigned short*)p)[idx]);
    return ((const float*)p)[idx];
}
__device__ __forceinline__ float4 load4f(const void* p, long idx, int bf) {
    float4 r;
    if (bf) {
        uint2 raw = *(const uint2*)((const unsigned short*)p + idx);
        r.x = bf2f((unsigned short)(raw.x & 0xFFFFu));
        r.y = bf2f((unsigned short)(raw.x >> 16));
        r.z = bf2f((unsigned short)(raw.y & 0xFFFFu));
        r.w = bf2f((unsigned short)(raw.y >> 16));
    } else {
        r = *(const float4*)((const float*)p + idx);
    }
    return r;
}

// ---------- dtype detection: bf16 N(0,1) ushorts have plausible exponents ----------
__global__ void detect_kernel(const void* xraw, int* flag) {
    __shared__ int cnt;
    if (threadIdx.x == 0) cnt = 0;
    __syncthreads();
    const unsigned short* u = (const unsigned short*)xraw;
    int good = 0;
    for (int i = threadIdx.x; i < 1024; i += 256) {
        unsigned short v = u[i];
        int e = (v >> 7) & 0xFF;
        if (v == 0 || (e >= 90 && e <= 141)) good++;
    }
    atomicAdd(&cnt, good);
    __syncthreads();
    if (threadIdx.x == 0) *flag = (cnt >= 900) ? 1 : 0;
}

// ---------- mask prep: self-detects bool8 / int32 / int64 / bf16 / f32 ----------
__global__ void mask_prep_kernel(const void* mraw, float* mflag, int n) {
    __shared__ int orA, orB, orC, orD;
    if (threadIdx.x == 0) { orA = 0; orB = 0; orC = 0; orD = 0; }
    __syncthreads();
    const unsigned char* p = (const unsigned char*)mraw;
    int a = 0, b = 0, c = 0, d = 0;
    for (int i = threadIdx.x; i < n; i += 256) {
        int v = p[i];
        a |= v & 0xFE;              // any byte not in {0,1} -> float encodings
        if ((i & 3) == 1) b |= v;   // bf16: high byte of even elems (0x3F); f32: always 0
        if (i & 3) c |= v;          // bool8: mask bytes; int32/64: 0
        if (i & 4) d |= v;          // int32: LSB of odd ints; int64: 0
    }
    if (a) atomicOr(&orA, 1);
    if (b) atomicOr(&orB, 1);
    if (c) atomicOr(&orC, 1);
    if (d) atomicOr(&orD, 1);
    __syncthreads();
    int mode;  // 0 bool8, 1 int32, 2 int64, 3 bf16, 4 f32
    if (orA) mode = orB ? 3 : 4;
    else if (orC) mode = 0;
    else mode = orD ? 1 : 2;
    for (int i = threadIdx.x; i < n; i += 256) {
        int v;
        switch (mode) {
            case 0: v = p[i]; break;
            case 1: v = ((const int*)p)[i]; break;
            case 2: v = (int)((const long long*)p)[i]; break;
            case 3: v = ((const unsigned short*)p)[i] != 0; break;
            default: v = (((const float*)p)[i] != 0.0f); break;
        }
        mflag[i] = v ? 1.0f : 0.0f;
    }
}

// ---------- small converts: dist_emb [L,50,8] + attn_bias [L,8] -> f32 ----------
__global__ void conv_small_kernel(const void* de, const void* ab,
                                  float* deo, float* abo, const int* flagp) {
    int bf = *flagp;
    int i = blockIdx.x * 256 + threadIdx.x;
    if (i < 1200) deo[i] = ldin(de, i, bf);
    if (i < 24) abo[i] = ldin(ab, i, bf);
}

// ---------- bins = clip(trunc(dist*10), 0, 49) ----------
__global__ void bins_kernel(const void* dist, unsigned char* bins,
                            const int* flagp, int n) {
    int bf = *flagp;
    int i = blockIdx.x * 256 + threadIdx.x;
    if (i < n) {
        float d = ldin(dist, i, bf);
        int v = (int)(d * 10.0f);
        v = v < 0 ? 0 : (v > 49 ? 49 : v);
        bins[i] = (unsigned char)v;
    }
}

// ---------- h init: f32 copy of x ----------
__global__ void init_h_kernel(const void* x, float* h, const int* flagp, int n) {
    int i = blockIdx.x * 256 + threadIdx.x;
    if (i < n) h[i] = ldin(x, i, *flagp);
}

// ---------- LayerNorm: one wave per row of 128 ----------
__global__ __launch_bounds__(256) void ln_kernel(
    const float* __restrict__ h, const void* graw, const void* braw, long off,
    float* __restrict__ out, const int* flagp) {
    int bf = *flagp;
    int row = blockIdx.x * 4 + (threadIdx.x >> 6);
    int lane = threadIdx.x & 63;
    const float* p = h + (size_t)row * Hq;
    float x0 = p[lane], x1 = p[lane + 64];
    float s = x0 + x1, s2 = x0 * x0 + x1 * x1;
#pragma unroll
    for (int o = 32; o; o >>= 1) {
        s += __shfl_xor(s, o);
        s2 += __shfl_xor(s2, o);
    }
    float mu = s * (1.0f / 128.0f);
    float var = fmaxf(s2 * (1.0f / 128.0f) - mu * mu, 0.0f);
    float r = rsqrtf(var + 1e-5f);
    float g0 = ldin(graw, off + lane, bf), g1v = ldin(graw, off + lane + 64, bf);
    float b0 = ldin(braw, off + lane, bf), b1v = ldin(braw, off + lane + 64, bf);
    out[(size_t)row * Hq + lane] = (x0 - mu) * r * g0 + b0;
    out[(size_t)row * Hq + lane + 64] = (x1 - mu) * r * g1v + b1v;
}

// ---------- generic fp32 GEMM: C[M,Nout] = A[M,K] @ W[K,Nout] + bias (+C) ----------
__global__ __launch_bounds__(256) void gemm_kernel(
    const float* __restrict__ A, const void* __restrict__ Wraw, long wOff,
    const void* __restrict__ braw, long bOff, float* __restrict__ C,
    int K, int Nout, int resid, const int* flagp) {
    int bf = *flagp;
    __shared__ float As[64][17];
    __shared__ float Ws[16][64];
    int tx = threadIdx.x & 15, ty = threadIdx.x >> 4;
    int m0 = blockIdx.x * 64, n0 = blockIdx.y * 64;
    int rowA = threadIdx.x >> 2;
    int kkA = (threadIdx.x & 3) * 4;
    float acc[4][4] = {};
    for (int k0 = 0; k0 < K; k0 += 16) {
        float4 a4 = *(const float4*)(A + (size_t)(m0 + rowA) * K + k0 + kkA);
        As[rowA][kkA + 0] = a4.x; As[rowA][kkA + 1] = a4.y;
        As[rowA][kkA + 2] = a4.z; As[rowA][kkA + 3] = a4.w;
        float4 w4 = load4f(Wraw, wOff + (long)(k0 + ty) * Nout + n0 + tx * 4, bf);
        *(float4*)&Ws[ty][tx * 4] = w4;
        __syncthreads();
#pragma unroll
        for (int k = 0; k < 16; ++k) {
            float bv[4];
            *(float4*)bv = *(const float4*)&Ws[k][tx * 4];
            float av[4];
#pragma unroll
            for (int i = 0; i < 4; ++i) av[i] = As[ty * 4 + i][k];
#pragma unroll
            for (int i = 0; i < 4; ++i)
#pragma unroll
                for (int j = 0; j < 4; ++j) acc[i][j] += av[i] * bv[j];
        }
        __syncthreads();
    }
#pragma unroll
    for (int i = 0; i < 4; ++i) {
        int m = m0 + ty * 4 + i;
#pragma unroll
        for (int j = 0; j < 4; ++j) {
            int n = n0 + tx * 4 + j;
            float c = acc[i][j] + ldin(braw, bOff + n, bf);
            float* dst = C + (size_t)m * Nout + n;
            if (resid) c += *dst;
            *dst = c;
        }
    }
}

// ---------- GLU GEMM: V[M,512] = (A@Wa+ba) * sigmoid(A@Wb+bb), K=128 ----------
__global__ __launch_bounds__(256) void glu_gemm_kernel(
    const float* __restrict__ A, const void* __restrict__ Wraw, long wOff,
    const void* __restrict__ braw, long bOff, float* __restrict__ Vout,
    const int* flagp) {
    int bf = *flagp;
    __shared__ float As[64][17];
    __shared__ float Wsa[16][64];
    __shared__ float Wsb[16][64];
    int tx = threadIdx.x & 15, ty = threadIdx.x >> 4;
    int m0 = blockIdx.x * 64, n0 = blockIdx.y * 64;
    int rowA = threadIdx.x >> 2;
    int kkA = (threadIdx.x & 3) * 4;
    float acca[4][4] = {};
    float accb[4][4] = {};
    for (int k0 = 0; k0 < 128; k0 += 16) {
        float4 a4 = *(const float4*)(A + (size_t)(m0 + rowA) * 128 + k0 + kkA);
        As[rowA][kkA + 0] = a4.x; As[rowA][kkA + 1] = a4.y;
        As[rowA][kkA + 2] = a4.z; As[rowA][kkA + 3] = a4.w;
        float4 wa = load4f(Wraw, wOff + (long)(k0 + ty) * 1024 + n0 + tx * 4, bf);
        float4 wb = load4f(Wraw, wOff + (long)(k0 + ty) * 1024 + 512 + n0 + tx * 4, bf);
        *(float4*)&Wsa[ty][tx * 4] = wa;
        *(float4*)&Wsb[ty][tx * 4] = wb;
        __syncthreads();
#pragma unroll
        for (int k = 0; k < 16; ++k) {
            float bva[4], bvb[4];
            *(float4*)bva = *(const float4*)&Wsa[k][tx * 4];
            *(float4*)bvb = *(const float4*)&Wsb[k][tx * 4];
            float av[4];
#pragma unroll
            for (int i = 0; i < 4; ++i) av[i] = As[ty * 4 + i][k];
#pragma unroll
            for (int i = 0; i < 4; ++i)
#pragma unroll
                for (int j = 0; j < 4; ++j) {
                    acca[i][j] += av[i] * bva[j];
                    accb[i][j] += av[i] * bvb[j];
                }
        }
        __syncthreads();
    }
#pragma unroll
    for (int i = 0; i < 4; ++i) {
        int m = m0 + ty * 4 + i;
#pragma unroll
        for (int j = 0; j < 4; ++j) {
            int n = n0 + tx * 4 + j;
            float ua = acca[i][j] + ldin(braw, bOff + n, bf);
            float ub = accb[i][j] + ldin(braw, bOff + 512 + n, bf);
            Vout[(size_t)m * 512 + n] = ua / (1.0f + __expf(-ub));
        }
    }
}

// ---------- attention: block = (64 q) x (b, nh); K/V staged transposed in 64KB LDS ----------
__global__ __launch_bounds__(256) void attn_kernel(
    const float* __restrict__ Q, const float* __restrict__ Kg,
    const float* __restrict__ Vg, const unsigned char* __restrict__ bins,
    const float* __restrict__ maskf, const float* __restrict__ deL,
    const float* __restrict__ abL, float* __restrict__ out) {
    __shared__ float KsT[16][512];
    __shared__ float VsT[16][512];
    int b = blockIdx.z, nh = blockIdx.y, q0 = blockIdx.x * 64;
    int tid = threadIdx.x;
    const float* Kp = Kg + ((size_t)b * Nq) * Hq + nh * HDq;
    const float* Vp = Vg + ((size_t)b * Nq) * Hq + nh * HDq;
    for (int j = tid; j < 2048; j += 256) {
        int k = j >> 2, c = (j & 3) * 4;
        float4 k4 = *(const float4*)(Kp + (size_t)k * Hq + c);
        KsT[c + 0][k] = k4.x; KsT[c + 1][k] = k4.y;
        KsT[c + 2][k] = k4.z; KsT[c + 3][k] = k4.w;
        float4 v4 = *(const float4*)(Vp + (size_t)k * Hq + c);
        VsT[c + 0][k] = v4.x; VsT[c + 1][k] = v4.y;
        VsT[c + 2][k] = v4.z; VsT[c + 3][k] = v4.w;
    }
    __syncthreads();
    int wave = tid >> 6, lane = tid & 63;
    // per-lane mask bitmask over its 8 k's (k = lane + 64*i)
    unsigned int mmask = 0;
#pragma unroll
    for (int i = 0; i < 8; ++i)
        if (maskf[(size_t)b * Nq + lane + i * 64] != 0.0f) mmask |= (1u << i);
    float ab = abL[nh];
    for (int t = 0; t < 8; ++t) {
        int q = q0 + wave * 16 + t * 2;
        const float* Qp0 = Q + ((size_t)(b * Nq + q)) * Hq + nh * HDq;
        const float* Qp1 = Qp0 + Hq;
        float qv0[16], qv1[16];
#pragma unroll
        for (int c = 0; c < 4; ++c) {
            float4 f0 = *(const float4*)(Qp0 + c * 4);
            float4 f1 = *(const float4*)(Qp1 + c * 4);
            qv0[c * 4 + 0] = f0.x; qv0[c * 4 + 1] = f0.y; qv0[c * 4 + 2] = f0.z; qv0[c * 4 + 3] = f0.w;
            qv1[c * 4 + 0] = f1.x; qv1[c * 4 + 1] = f1.y; qv1[c * 4 + 2] = f1.z; qv1[c * 4 + 3] = f1.w;
        }
        const unsigned char* br0 = bins + ((size_t)(b * Nq + q)) * Nq;
        const unsigned char* br1 = br0 + Nq;
        float s0[8], s1[8];
        float m0 = -1e30f, m1 = -1e30f;
#pragma unroll
        for (int i = 0; i < 8; ++i) {
            int k = lane + i * 64;
            float a0 = 0.0f, a1 = 0.0f;
#pragma unroll
            for (int d = 0; d < 16; ++d) {
                float kv = KsT[d][k];
                a0 += qv0[d] * kv;
                a1 += qv1[d] * kv;
            }
            float bias0 = deL[(int)br0[k] * NHq + nh] + ab;
            float bias1 = deL[(int)br1[k] * NHq + nh] + ab;
            float sc0 = a0 * 0.25f + bias0;
            float sc1 = a1 * 0.25f + bias1;
            bool msk = (mmask >> i) & 1;
            sc0 = msk ? -1e9f : sc0;
            sc1 = msk ? -1e9f : sc1;
            s0[i] = sc0; s1[i] = sc1;
            m0 = fmaxf(m0, sc0); m1 = fmaxf(m1, sc1);
        }
#pragma unroll
        for (int o = 32; o; o >>= 1) {
            m0 = fmaxf(m0, __shfl_xor(m0, o));
            m1 = fmaxf(m1, __shfl_xor(m1, o));
        }
        float z0 = 0.0f, z1 = 0.0f;
        float o0[16], o1[16];
#pragma unroll
        for (int d = 0; d < 16; ++d) { o0[d] = 0.0f; o1[d] = 0.0f; }
#pragma unroll
        for (int i = 0; i < 8; ++i) {
            int k = lane + i * 64;
            float p0 = __expf(s0[i] - m0);
            float p1 = __expf(s1[i] - m1);
            z0 += p0; z1 += p1;
#pragma unroll
            for (int d = 0; d < 16; ++d) {
                float vv = VsT[d][k];
                o0[d] += p0 * vv;
                o1[d] += p1 * vv;
            }
        }
#pragma unroll
        for (int o = 32; o; o >>= 1) {
            z0 += __shfl_xor(z0, o);
            z1 += __shfl_xor(z1, o);
        }
        float r0 = 1.0f / z0, r1 = 1.0f / z1;
        float res0 = 0.0f, res1 = 0.0f;
#pragma unroll
        for (int d = 0; d < 16; ++d) {
            float v0 = o0[d], v1 = o1[d];
#pragma unroll
            for (int o = 32; o; o >>= 1) {
                v0 += __shfl_xor(v0, o);
                v1 += __shfl_xor(v1, o);
            }
            if (lane == d) { res0 = v0; res1 = v1; }
        }
        if (lane < 16) {
            out[((size_t)(b * Nq + q)) * Hq + nh * HDq + lane] = res0 * r0;
            out[((size_t)(b * Nq + q + 1)) * Hq + nh * HDq + lane] = res1 * r1;
        }
    }
}

// ---------- output: h(f32) -> d_out (bf16 RNE if inputs were bf16, else f32) ----------
__global__ void out_kernel(const float* __restrict__ h, void* out,
                           const int* flagp, int n) {
    int bf = *flagp;
    int i = blockIdx.x * 256 + threadIdx.x;
    if (i < n) {
        float v = h[i];
        if (bf) {
            unsigned int u = __float_as_uint(v);
            unsigned int r = (u + 0x7FFFu + ((u >> 16) & 1u)) >> 16;
            ((unsigned short*)out)[i] = (unsigned short)r;
        } else {
            ((float*)out)[i] = v;
        }
    }
}

extern "C" void kernel_launch(void* const* d_in, const int* in_sizes, int n_in,
                              void* d_out, int out_size, void* d_ws, size_t ws_size,
                              hipStream_t stream) {
    const void* x  = d_in[0];
    const void* dist = d_in[1];
    const void* mask = d_in[2];
    const void* Wq = d_in[3];  const void* bq = d_in[4];
    const void* Wk = d_in[5];  const void* bk = d_in[6];
    const void* Wv = d_in[7];  const void* bv = d_in[8];
    const void* Wo = d_in[9];  const void* bo = d_in[10];
    const void* de = d_in[11]; const void* ab = d_in[12];
    const void* g1 = d_in[13]; const void* b1 = d_in[14];
    const void* g2 = d_in[15]; const void* b2 = d_in[16];
    const void* Wf1 = d_in[17]; const void* bf1 = d_in[18];
    const void* Wf2 = d_in[19]; const void* bf2 = d_in[20];

    // workspace layout (bytes)
    char* ws = (char*)d_ws;
    const size_t OFF_DE   = 64;                       // 1200 f32
    const size_t OFF_AB   = 5120;                     // 24 f32
    const size_t OFF_BINS = 8192;                     // 8,388,608 u8
    const size_t OFF_MSK  = OFF_BINS + 8388608;       // 65,536 B
    const size_t OFF_H    = OFF_MSK + 65536;          // 8,388,608 B f32
    const size_t OFF_A    = OFF_H + 8388608;          // 33,554,432 B (hn,Q,K,V | vglu)
    const size_t OFF_ATT  = OFF_A + 33554432;         // 8,388,608 B (attn_out | hn2)
    const size_t NEEDED   = OFF_ATT + 8388608;
    if (ws_size < NEEDED) return;  // refuse to corrupt memory

    int* flag = (int*)ws;
    float* deF = (float*)(ws + OFF_DE);
    float* abF = (float*)(ws + OFF_AB);
    unsigned char* bins = (unsigned char*)(ws + OFF_BINS);
    float* maskf = (float*)(ws + OFF_MSK);
    float* h = (float*)(ws + OFF_H);
    float* regA = (float*)(ws + OFF_A);
    float* hn = regA;
    float* Qb = regA + 2097152;
    float* Kb = regA + 2 * 2097152;
    float* Vb = regA + 3 * 2097152;
    float* vglu = regA;
    float* att = (float*)(ws + OFF_ATT);

    detect_kernel<<<1, 256, 0, stream>>>(x, flag);
    conv_small_kernel<<<5, 256, 0, stream>>>(de, ab, deF, abF, flag);
    mask_prep_kernel<<<1, 256, 0, stream>>>(mask, maskf, Bq * Nq);
    bins_kernel<<<32768, 256, 0, stream>>>(dist, bins, flag, Bq * Nq * Nq);
    init_h_kernel<<<8192, 256, 0, stream>>>(x, h, flag, Mq * Hq);

    dim3 gg(256, 2);
    dim3 ga(8, NHq, Bq);
    dim3 gu(256, 8);
    for (int l = 0; l < 3; ++l) {
        ln_kernel<<<4096, 256, 0, stream>>>(h, g1, b1, (long)l * Hq, hn, flag);
        gemm_kernel<<<gg, 256, 0, stream>>>(hn, Wq, (long)l * Hq * Hq, bq, (long)l * Hq,
                                            Qb, Hq, Hq, 0, flag);
        gemm_kernel<<<gg, 256, 0, stream>>>(hn, Wk, (long)l * Hq * Hq, bk, (long)l * Hq,
                                            Kb, Hq, Hq, 0, flag);
        gemm_kernel<<<gg, 256, 0, stream>>>(hn, Wv, (long)l * Hq * Hq, bv, (long)l * Hq,
                                            Vb, Hq, Hq, 0, flag);
        attn_kernel<<<ga, 256, 0, stream>>>(Qb, Kb, Vb, bins, maskf,
                                            deF + (long)l * 50 * NHq, abF + (long)l * NHq, att);
        gemm_kernel<<<gg, 256, 0, stream>>>(att, Wo, (long)l * Hq * Hq, bo, (long)l * Hq,
                                            h, Hq, Hq, 1, flag);
        ln_kernel<<<4096, 256, 0, stream>>>(h, g2, b2, (long)l * Hq, att, flag);
        glu_gemm_kernel<<<gu, 256, 0, stream>>>(att, Wf1, (long)l * Hq * 1024, bf1,
                                                (long)l * 1024, vglu, flag);
        gemm_kernel<<<gg, 256, 0, stream>>>(vglu, Wf2, (long)l * 512 * Hq, bf2, (long)l * Hq,
                                            h, 512, Hq, 1, flag);
    }
    out_kernel<<<8192, 256, 0, stream>>>(h, d_out, flag, Mq * Hq);
}

// Round 2
// 1016.433 us; speedup vs baseline: 2.3626x; 2.3626x over previous
//
#include <hip/hip_runtime.h>
#include <stdint.h>

#define Bq 32
#define Nq 512
#define Hq 128
#define NHq 8
#define HDq 16
#define Mq (Bq * Nq)   // 16384

// ---------- dtype-flex helpers (flag: 1 = inputs are bf16, 0 = f32) ----------
__device__ __forceinline__ float bf2f(unsigned short v) {
    return __uint_as_float(((unsigned int)v) << 16);
}
__device__ __forceinline__ float ldin(const void* p, long idx, int bf) {
    if (bf) return bf2f(((const unsigned short*)p)[idx]);
    return ((const float*)p)[idx];
}
__device__ __forceinline__ float4 load4f(const void* p, long idx, int bf) {
    float4 r;
    if (bf) {
        uint2 raw = *(const uint2*)((const unsigned short*)p + idx);
        r.x = bf2f((unsigned short)(raw.x & 0xFFFFu));
        r.y = bf2f((unsigned short)(raw.x >> 16));
        r.z = bf2f((unsigned short)(raw.y & 0xFFFFu));
        r.w = bf2f((unsigned short)(raw.y >> 16));
    } else {
        r = *(const float4*)((const float*)p + idx);
    }
    return r;
}

// ---------- dtype detection: bf16 N(0,1) ushorts have plausible exponents ----------
__global__ void detect_kernel(const void* xraw, int* flag) {
    __shared__ int cnt;
    if (threadIdx.x == 0) cnt = 0;
    __syncthreads();
    const unsigned short* u = (const unsigned short*)xraw;
    int good = 0;
    for (int i = threadIdx.x; i < 1024; i += 256) {
        unsigned short v = u[i];
        int e = (v >> 7) & 0xFF;
        if (v == 0 || (e >= 90 && e <= 141)) good++;
    }
    atomicAdd(&cnt, good);
    __syncthreads();
    if (threadIdx.x == 0) *flag = (cnt >= 900) ? 1 : 0;
}

// ---------- mask prep: self-detects encoding, emits bit-words (1 = masked) ----------
// word layout: mbits[b*16 + w] bit j = mask[b, w*32+j]
__global__ void mask_prep_kernel(const void* mraw, unsigned* mbits, int n) {
    __shared__ int orA, orB, orC, orD;
    if (threadIdx.x == 0) { orA = 0; orB = 0; orC = 0; orD = 0; }
    __syncthreads();
    const unsigned char* p = (const unsigned char*)mraw;
    int a = 0, b = 0, c = 0, d = 0;
    for (int i = threadIdx.x; i < n; i += 256) {
        int v = p[i];
        a |= v & 0xFE;              // any byte not in {0,1} -> float encodings
        if ((i & 3) == 1) b |= v;   // bf16 high byte (0x3F) vs f32 (0)
        if (i & 3) c |= v;          // bool8 vs int32/64
        if (i & 4) d |= v;          // int32 vs int64
    }
    if (a) atomicOr(&orA, 1);
    if (b) atomicOr(&orB, 1);
    if (c) atomicOr(&orC, 1);
    if (d) atomicOr(&orD, 1);
    __syncthreads();
    int mode;  // 0 bool8, 1 int32, 2 int64, 3 bf16, 4 f32
    if (orA) mode = orB ? 3 : 4;
    else if (orC) mode = 0;
    else mode = orD ? 1 : 2;
    for (int wI = threadIdx.x; wI < n / 32; wI += 256) {
        unsigned word = 0;
        for (int j = 0; j < 32; ++j) {
            int i = wI * 32 + j;
            int v;
            switch (mode) {
                case 0: v = p[i]; break;
                case 1: v = ((const int*)p)[i]; break;
                case 2: v = (int)((const long long*)p)[i]; break;
                case 3: v = ((const unsigned short*)p)[i] != 0; break;
                default: v = (((const float*)p)[i] != 0.0f); break;
            }
            if (v) word |= 1u << j;
        }
        mbits[wI] = word;
    }
}

// ---------- small converts: dist_emb [L,50,8] + attn_bias [L,8] -> f32 ----------
__global__ void conv_small_kernel(const void* de, const void* ab,
                                  float* deo, float* abo, const int* flagp) {
    int bf = *flagp;
    int i = blockIdx.x * 256 + threadIdx.x;
    if (i < 1200) deo[i] = ldin(de, i, bf);
    if (i < 24) abo[i] = ldin(ab, i, bf);
}

// ---------- bins = clip(trunc(dist*10), 0, 49) ----------
__global__ void bins_kernel(const void* dist, unsigned char* bins,
                            const int* flagp, int n) {
    int bf = *flagp;
    int i = blockIdx.x * 256 + threadIdx.x;
    if (i < n) {
        float d = ldin(dist, i, bf);
        int v = (int)(d * 10.0f);
        v = v < 0 ? 0 : (v > 49 ? 49 : v);
        bins[i] = (unsigned char)v;
    }
}

// ---------- h init: f32 copy of x ----------
__global__ void init_h_kernel(const void* x, float* h, const int* flagp, int n) {
    int i = blockIdx.x * 256 + threadIdx.x;
    if (i < n) h[i] = ldin(x, i, *flagp);
}

// ---------- LayerNorm: one wave per row of 128 ----------
__global__ __launch_bounds__(256) void ln_kernel(
    const float* __restrict__ h, const void* graw, const void* braw, long off,
    float* __restrict__ out, const int* flagp) {
    int bf = *flagp;
    int row = blockIdx.x * 4 + (threadIdx.x >> 6);
    int lane = threadIdx.x & 63;
    const float* p = h + (size_t)row * Hq;
    float x0 = p[lane], x1 = p[lane + 64];
    float s = x0 + x1, s2 = x0 * x0 + x1 * x1;
#pragma unroll
    for (int o = 32; o; o >>= 1) {
        s += __shfl_xor(s, o);
        s2 += __shfl_xor(s2, o);
    }
    float mu = s * (1.0f / 128.0f);
    float var = fmaxf(s2 * (1.0f / 128.0f) - mu * mu, 0.0f);
    float r = rsqrtf(var + 1e-5f);
    float g0 = ldin(graw, off + lane, bf), g1v = ldin(graw, off + lane + 64, bf);
    float b0 = ldin(braw, off + lane, bf), b1v = ldin(braw, off + lane + 64, bf);
    out[(size_t)row * Hq + lane] = (x0 - mu) * r * g0 + b0;
    out[(size_t)row * Hq + lane + 64] = (x1 - mu) * r * g1v + b1v;
}

// ---------- generic fp32 GEMM: C[M,Nout] = A[M,K] @ W[K,Nout] + bias (+C) ----------
__global__ __launch_bounds__(256) void gemm_kernel(
    const float* __restrict__ A, const void* __restrict__ Wraw, long wOff,
    const void* __restrict__ braw, long bOff, float* __restrict__ C,
    int K, int Nout, int resid, const int* flagp) {
    int bf = *flagp;
    __shared__ float As[64][17];
    __shared__ float Ws[16][64];
    int tx = threadIdx.x & 15, ty = threadIdx.x >> 4;
    int m0 = blockIdx.x * 64, n0 = blockIdx.y * 64;
    int rowA = threadIdx.x >> 2;
    int kkA = (threadIdx.x & 3) * 4;
    float acc[4][4] = {};
    for (int k0 = 0; k0 < K; k0 += 16) {
        float4 a4 = *(const float4*)(A + (size_t)(m0 + rowA) * K + k0 + kkA);
        As[rowA][kkA + 0] = a4.x; As[rowA][kkA + 1] = a4.y;
        As[rowA][kkA + 2] = a4.z; As[rowA][kkA + 3] = a4.w;
        float4 w4 = load4f(Wraw, wOff + (long)(k0 + ty) * Nout + n0 + tx * 4, bf);
        *(float4*)&Ws[ty][tx * 4] = w4;
        __syncthreads();
#pragma unroll
        for (int k = 0; k < 16; ++k) {
            float bv[4];
            *(float4*)bv = *(const float4*)&Ws[k][tx * 4];
            float av[4];
#pragma unroll
            for (int i = 0; i < 4; ++i) av[i] = As[ty * 4 + i][k];
#pragma unroll
            for (int i = 0; i < 4; ++i)
#pragma unroll
                for (int j = 0; j < 4; ++j) acc[i][j] += av[i] * bv[j];
        }
        __syncthreads();
    }
#pragma unroll
    for (int i = 0; i < 4; ++i) {
        int m = m0 + ty * 4 + i;
#pragma unroll
        for (int j = 0; j < 4; ++j) {
            int n = n0 + tx * 4 + j;
            float c = acc[i][j] + ldin(braw, bOff + n, bf);
            float* dst = C + (size_t)m * Nout + n;
            if (resid) c += *dst;
            *dst = c;
        }
    }
}

// ---------- GLU GEMM: V[M,512] = (A@Wa+ba) * sigmoid(A@Wb+bb), K=128 ----------
__global__ __launch_bounds__(256) void glu_gemm_kernel(
    const float* __restrict__ A, const void* __restrict__ Wraw, long wOff,
    const void* __restrict__ braw, long bOff, float* __restrict__ Vout,
    const int* flagp) {
    int bf = *flagp;
    __shared__ float As[64][17];
    __shared__ float Wsa[16][64];
    __shared__ float Wsb[16][64];
    int tx = threadIdx.x & 15, ty = threadIdx.x >> 4;
    int m0 = blockIdx.x * 64, n0 = blockIdx.y * 64;
    int rowA = threadIdx.x >> 2;
    int kkA = (threadIdx.x & 3) * 4;
    float acca[4][4] = {};
    float accb[4][4] = {};
    for (int k0 = 0; k0 < 128; k0 += 16) {
        float4 a4 = *(const float4*)(A + (size_t)(m0 + rowA) * 128 + k0 + kkA);
        As[rowA][kkA + 0] = a4.x; As[rowA][kkA + 1] = a4.y;
        As[rowA][kkA + 2] = a4.z; As[rowA][kkA + 3] = a4.w;
        float4 wa = load4f(Wraw, wOff + (long)(k0 + ty) * 1024 + n0 + tx * 4, bf);
        float4 wb = load4f(Wraw, wOff + (long)(k0 + ty) * 1024 + 512 + n0 + tx * 4, bf);
        *(float4*)&Wsa[ty][tx * 4] = wa;
        *(float4*)&Wsb[ty][tx * 4] = wb;
        __syncthreads();
#pragma unroll
        for (int k = 0; k < 16; ++k) {
            float bva[4], bvb[4];
            *(float4*)bva = *(const float4*)&Wsa[k][tx * 4];
            *(float4*)bvb = *(const float4*)&Wsb[k][tx * 4];
            float av[4];
#pragma unroll
            for (int i = 0; i < 4; ++i) av[i] = As[ty * 4 + i][k];
#pragma unroll
            for (int i = 0; i < 4; ++i)
#pragma unroll
                for (int j = 0; j < 4; ++j) {
                    acca[i][j] += av[i] * bva[j];
                    accb[i][j] += av[i] * bvb[j];
                }
        }
        __syncthreads();
    }
#pragma unroll
    for (int i = 0; i < 4; ++i) {
        int m = m0 + ty * 4 + i;
#pragma unroll
        for (int j = 0; j < 4; ++j) {
            int n = n0 + tx * 4 + j;
            float ua = acca[i][j] + ldin(braw, bOff + n, bf);
            float ub = accb[i][j] + ldin(braw, bOff + 512 + n, bf);
            Vout[(size_t)m * 512 + n] = ua / (1.0f + __expf(-ub));
        }
    }
}

// ---------- attention v2: lane owns one q row; K/V broadcast from LDS ----------
// grid = (2, NH, B); block = 256 (4 waves); wave w lane l -> q = bx*256 + w*64 + l
// Fixed-shift softmax (shift-invariant; scores O(10), no overflow). Masked k
// produce p = 0 exactly in the reference (exp(-1e9 - m) underflows), so we
// SKIP masked k entirely (wave-uniform branch, ~50% work cut).
__global__ __launch_bounds__(256) void attn_kernel(
    const float* __restrict__ Q, const float* __restrict__ Kg,
    const float* __restrict__ Vg, const unsigned char* __restrict__ bins,
    const unsigned int* __restrict__ mbits, const float* __restrict__ deL,
    const float* __restrict__ abL, float* __restrict__ out) {
    __shared__ float4 Ks[Nq * 4];   // [k][d/4] row-contiguous, 32 KB
    __shared__ float4 Vs[Nq * 4];
    int b = blockIdx.z, nh = blockIdx.y;
    int tid = threadIdx.x;
    const float* Kp = Kg + ((size_t)b * Nq) * Hq + nh * HDq;
    const float* Vp = Vg + ((size_t)b * Nq) * Hq + nh * HDq;
    for (int j = tid; j < Nq * 4; j += 256) {
        int k = j >> 2, c = j & 3;
        Ks[j] = *(const float4*)(Kp + (size_t)k * Hq + c * 4);
        Vs[j] = *(const float4*)(Vp + (size_t)k * Hq + c * 4);
    }
    __syncthreads();
    int wave = tid >> 6, lane = tid & 63;
    int q = blockIdx.x * 256 + wave * 64 + lane;
    // bias table (<=50 entries) lives in a register, gathered via __shfl
    float tbl = (lane < 50) ? deL[lane * NHq + nh] + abL[nh] : 0.0f;
    unsigned mwall = (lane < 16) ? mbits[b * 16 + lane] : 0u;
    const float* Qp = Q + ((size_t)(b * Nq + q)) * Hq + nh * HDq;
    float4 qa = *(const float4*)(Qp);
    float4 qb = *(const float4*)(Qp + 4);
    float4 qc = *(const float4*)(Qp + 8);
    float4 qd = *(const float4*)(Qp + 12);
    const unsigned char* brow = bins + ((size_t)(b * Nq + q)) * Nq;
    float o[16];
#pragma unroll
    for (int d = 0; d < 16; ++d) o[d] = 0.0f;
    float z = 0.0f;
    for (int k32 = 0; k32 < 16; ++k32) {
        unsigned w = (unsigned)__shfl((int)mwall, k32);  // uniform key-mask word
        if (w == 0xFFFFFFFFu) continue;
        const unsigned* b32p = (const unsigned*)(brow + k32 * 32);
#pragma unroll 2
        for (int kg = 0; kg < 8; ++kg) {
            unsigned bv4 = b32p[kg];
#pragma unroll
            for (int j = 0; j < 4; ++j) {
                if (!((w >> (kg * 4 + j)) & 1u)) {
                    int kk = k32 * 32 + kg * 4 + j;
                    float4 ka = Ks[kk * 4 + 0];
                    float4 kb = Ks[kk * 4 + 1];
                    float4 kc = Ks[kk * 4 + 2];
                    float4 kd = Ks[kk * 4 + 3];
                    float s0 = qa.x * ka.x + qa.y * ka.y + qa.z * ka.z + qa.w * ka.w;
                    float s1 = qb.x * kb.x + qb.y * kb.y + qb.z * kb.z + qb.w * kb.w;
                    float s2 = qc.x * kc.x + qc.y * kc.y + qc.z * kc.z + qc.w * kc.w;
                    float s3 = qd.x * kd.x + qd.y * kd.y + qd.z * kd.z + qd.w * kd.w;
                    float bias = __shfl(tbl, (int)((bv4 >> (8 * j)) & 0xFFu));
                    float s = ((s0 + s1) + (s2 + s3)) * 0.25f + bias;
                    float p = __expf(s);
                    z += p;
                    float4 va = Vs[kk * 4 + 0];
                    float4 vb = Vs[kk * 4 + 1];
                    float4 vc = Vs[kk * 4 + 2];
                    float4 vd = Vs[kk * 4 + 3];
                    o[0] += p * va.x;  o[1] += p * va.y;  o[2] += p * va.z;  o[3] += p * va.w;
                    o[4] += p * vb.x;  o[5] += p * vb.y;  o[6] += p * vb.z;  o[7] += p * vb.w;
                    o[8] += p * vc.x;  o[9] += p * vc.y;  o[10] += p * vc.z; o[11] += p * vc.w;
                    o[12] += p * vd.x; o[13] += p * vd.y; o[14] += p * vd.z; o[15] += p * vd.w;
                }
            }
        }
    }
    float r = 1.0f / fmaxf(z, 1e-35f);
    float* op = out + ((size_t)(b * Nq + q)) * Hq + nh * HDq;
    *(float4*)(op + 0)  = make_float4(o[0] * r,  o[1] * r,  o[2] * r,  o[3] * r);
    *(float4*)(op + 4)  = make_float4(o[4] * r,  o[5] * r,  o[6] * r,  o[7] * r);
    *(float4*)(op + 8)  = make_float4(o[8] * r,  o[9] * r,  o[10] * r, o[11] * r);
    *(float4*)(op + 12) = make_float4(o[12] * r, o[13] * r, o[14] * r, o[15] * r);
}

// ---------- output: h(f32) -> d_out (bf16 RNE if inputs were bf16, else f32) ----------
__global__ void out_kernel(const float* __restrict__ h, void* out,
                           const int* flagp, int n) {
    int bf = *flagp;
    int i = blockIdx.x * 256 + threadIdx.x;
    if (i < n) {
        float v = h[i];
        if (bf) {
            unsigned int u = __float_as_uint(v);
            unsigned int r = (u + 0x7FFFu + ((u >> 16) & 1u)) >> 16;
            ((unsigned short*)out)[i] = (unsigned short)r;
        } else {
            ((float*)out)[i] = v;
        }
    }
}

extern "C" void kernel_launch(void* const* d_in, const int* in_sizes, int n_in,
                              void* d_out, int out_size, void* d_ws, size_t ws_size,
                              hipStream_t stream) {
    const void* x  = d_in[0];
    const void* dist = d_in[1];
    const void* mask = d_in[2];
    const void* Wq = d_in[3];  const void* bq = d_in[4];
    const void* Wk = d_in[5];  const void* bk = d_in[6];
    const void* Wv = d_in[7];  const void* bv = d_in[8];
    const void* Wo = d_in[9];  const void* bo = d_in[10];
    const void* de = d_in[11]; const void* ab = d_in[12];
    const void* g1 = d_in[13]; const void* b1 = d_in[14];
    const void* g2 = d_in[15]; const void* b2 = d_in[16];
    const void* Wf1 = d_in[17]; const void* bf1 = d_in[18];
    const void* Wf2 = d_in[19]; const void* bf2 = d_in[20];

    // workspace layout (bytes)
    char* ws = (char*)d_ws;
    const size_t OFF_DE   = 64;                       // 1200 f32
    const size_t OFF_AB   = 5120;                     // 24 f32
    const size_t OFF_BINS = 8192;                     // 8,388,608 u8
    const size_t OFF_MSK  = OFF_BINS + 8388608;       // 2,048 B (512 u32 words)
    const size_t OFF_H    = OFF_MSK + 65536;          // 8,388,608 B f32
    const size_t OFF_A    = OFF_H + 8388608;          // 33,554,432 B (hn,Q,K,V | vglu)
    const size_t OFF_ATT  = OFF_A + 33554432;         // 8,388,608 B (attn_out | hn2)
    const size_t NEEDED   = OFF_ATT + 8388608;
    if (ws_size < NEEDED) return;  // refuse to corrupt memory

    int* flag = (int*)ws;
    float* deF = (float*)(ws + OFF_DE);
    float* abF = (float*)(ws + OFF_AB);
    unsigned char* bins = (unsigned char*)(ws + OFF_BINS);
    unsigned* mbits = (unsigned*)(ws + OFF_MSK);
    float* h = (float*)(ws + OFF_H);
    float* regA = (float*)(ws + OFF_A);
    float* hn = regA;
    float* Qb = regA + 2097152;
    float* Kb = regA + 2 * 2097152;
    float* Vb = regA + 3 * 2097152;
    float* vglu = regA;
    float* att = (float*)(ws + OFF_ATT);

    detect_kernel<<<1, 256, 0, stream>>>(x, flag);
    conv_small_kernel<<<5, 256, 0, stream>>>(de, ab, deF, abF, flag);
    mask_prep_kernel<<<1, 256, 0, stream>>>(mask, mbits, Bq * Nq);
    bins_kernel<<<32768, 256, 0, stream>>>(dist, bins, flag, Bq * Nq * Nq);
    init_h_kernel<<<8192, 256, 0, stream>>>(x, h, flag, Mq * Hq);

    dim3 gg(256, 2);
    dim3 ga(2, NHq, Bq);
    dim3 gu(256, 8);
    for (int l = 0; l < 3; ++l) {
        ln_kernel<<<4096, 256, 0, stream>>>(h, g1, b1, (long)l * Hq, hn, flag);
        gemm_kernel<<<gg, 256, 0, stream>>>(hn, Wq, (long)l * Hq * Hq, bq, (long)l * Hq,
                                            Qb, Hq, Hq, 0, flag);
        gemm_kernel<<<gg, 256, 0, stream>>>(hn, Wk, (long)l * Hq * Hq, bk, (long)l * Hq,
                                            Kb, Hq, Hq, 0, flag);
        gemm_kernel<<<gg, 256, 0, stream>>>(hn, Wv, (long)l * Hq * Hq, bv, (long)l * Hq,
                                            Vb, Hq, Hq, 0, flag);
        attn_kernel<<<ga, 256, 0, stream>>>(Qb, Kb, Vb, bins, mbits,
                                            deF + (long)l * 50 * NHq, abF + (long)l * NHq, att);
        gemm_kernel<<<gg, 256, 0, stream>>>(att, Wo, (long)l * Hq * Hq, bo, (long)l * Hq,
                                            h, Hq, Hq, 1, flag);
        ln_kernel<<<4096, 256, 0, stream>>>(h, g2, b2, (long)l * Hq, att, flag);
        glu_gemm_kernel<<<gu, 256, 0, stream>>>(att, Wf1, (long)l * Hq * 1024, bf1,
                                                (long)l * 1024, vglu, flag);
        gemm_kernel<<<gg, 256, 0, stream>>>(vglu, Wf2, (long)l * 512 * Hq, bf2, (long)l * Hq,
                                            h, 512, Hq, 1, flag);
    }
    out_kernel<<<8192, 256, 0, stream>>>(h, d_out, flag, Mq * Hq);
}

// Round 3
// 689.110 us; speedup vs baseline: 3.4848x; 1.4750x over previous
//
#include <hip/hip_runtime.h>
#include <stdint.h>

#define Bq 32
#define Nq 512
#define Hq 128
#define NHq 8
#define HDq 16
#define Mq (Bq * Nq)   // 16384

typedef unsigned short u16;
typedef __attribute__((ext_vector_type(8))) short short8;
typedef __attribute__((ext_vector_type(4))) float f32x4;

// ---------- dtype-flex helpers (flag: 1 = inputs are bf16, 0 = f32) ----------
__device__ __forceinline__ float bf2f(u16 v) {
    return __uint_as_float(((unsigned int)v) << 16);
}
__device__ __forceinline__ float ldin(const void* p, long idx, int bf) {
    if (bf) return bf2f(((const u16*)p)[idx]);
    return ((const float*)p)[idx];
}
__device__ __forceinline__ u16 f2bf(float v) {   // RNE; lossless for exact bf16
    unsigned int u = __float_as_uint(v);
    return (u16)((u + 0x7FFFu + ((u >> 16) & 1u)) >> 16);
}

// ---------- dtype detection ----------
__global__ void detect_kernel(const void* xraw, int* flag) {
    __shared__ int cnt;
    if (threadIdx.x == 0) cnt = 0;
    __syncthreads();
    const u16* u = (const u16*)xraw;
    int good = 0;
    for (int i = threadIdx.x; i < 1024; i += 256) {
        u16 v = u[i];
        int e = (v >> 7) & 0xFF;
        if (v == 0 || (e >= 90 && e <= 141)) good++;
    }
    atomicAdd(&cnt, good);
    __syncthreads();
    if (threadIdx.x == 0) *flag = (cnt >= 900) ? 1 : 0;
}

// ---------- mask prep -> bit-words (1 = masked) ----------
__global__ void mask_prep_kernel(const void* mraw, unsigned* mbits, int n) {
    __shared__ int orA, orB, orC, orD;
    if (threadIdx.x == 0) { orA = 0; orB = 0; orC = 0; orD = 0; }
    __syncthreads();
    const unsigned char* p = (const unsigned char*)mraw;
    int a = 0, b = 0, c = 0, d = 0;
    for (int i = threadIdx.x; i < n; i += 256) {
        int v = p[i];
        a |= v & 0xFE;
        if ((i & 3) == 1) b |= v;
        if (i & 3) c |= v;
        if (i & 4) d |= v;
    }
    if (a) atomicOr(&orA, 1);
    if (b) atomicOr(&orB, 1);
    if (c) atomicOr(&orC, 1);
    if (d) atomicOr(&orD, 1);
    __syncthreads();
    int mode;  // 0 bool8, 1 int32, 2 int64, 3 bf16, 4 f32
    if (orA) mode = orB ? 3 : 4;
    else if (orC) mode = 0;
    else mode = orD ? 1 : 2;
    for (int wI = threadIdx.x; wI < n / 32; wI += 256) {
        unsigned word = 0;
        for (int j = 0; j < 32; ++j) {
            int i = wI * 32 + j;
            int v;
            switch (mode) {
                case 0: v = p[i]; break;
                case 1: v = ((const int*)p)[i]; break;
                case 2: v = (int)((const long long*)p)[i]; break;
                case 3: v = ((const u16*)p)[i] != 0; break;
                default: v = (((const float*)p)[i] != 0.0f); break;
            }
            if (v) word |= 1u << j;
        }
        mbits[wI] = word;
    }
}

// ---------- small converts ----------
__global__ void conv_small_kernel(const void* de, const void* ab,
                                  float* deo, float* abo, const int* flagp) {
    int bf = *flagp;
    int i = blockIdx.x * 256 + threadIdx.x;
    if (i < 1200) deo[i] = ldin(de, i, bf);
    if (i < 24) abo[i] = ldin(ab, i, bf);
}

// ---------- bins ----------
__global__ void bins_kernel(const void* dist, unsigned char* bins,
                            const int* flagp, int n) {
    int bf = *flagp;
    int i = blockIdx.x * 256 + threadIdx.x;
    if (i < n) {
        float d = ldin(dist, i, bf);
        int v = (int)(d * 10.0f);
        v = v < 0 ? 0 : (v > 49 ? 49 : v);
        bins[i] = (unsigned char)v;
    }
}

// ---------- h init ----------
__global__ void init_h_kernel(const void* x, float* h, const int* flagp, int n) {
    int i = blockIdx.x * 256 + threadIdx.x;
    if (i < n) h[i] = ldin(x, i, *flagp);
}

// ---------- weight transpose: W[K][N] (any dtype) -> WT[N][K] bf16, 32x32 LDS tiles ----
// tiles per layer: q16,k16,v16,o16, f1:128, f2:64  => 256/layer, 768 total
__global__ __launch_bounds__(256) void wtrans_kernel(
    const void* Wqr, const void* Wkr, const void* Wvr, const void* Wor,
    const void* Wf1r, const void* Wf2r,
    u16* qkvT, u16* oT, u16* f1T, u16* f2T, const int* flagp) {
    int bf = *flagp;
    int bid = blockIdx.x;
    int l = bid >> 8, r = bid & 255;
    const void* src; u16* dst; long soff, doff; int Kd, Nd, t;
    if (r < 64) {
        int mat = r >> 4; t = r & 15; Kd = 128; Nd = 128;
        soff = (long)l * 16384;
        if (mat == 0)      { src = Wqr; dst = qkvT; doff = (long)l * 49152; }
        else if (mat == 1) { src = Wkr; dst = qkvT; doff = (long)l * 49152 + 16384; }
        else if (mat == 2) { src = Wvr; dst = qkvT; doff = (long)l * 49152 + 32768; }
        else               { src = Wor; dst = oT;   doff = (long)l * 16384; }
    } else if (r < 192) {
        t = r - 64; Kd = 128; Nd = 1024;
        src = Wf1r; soff = (long)l * 131072; dst = f1T; doff = (long)l * 131072;
    } else {
        t = r - 192; Kd = 512; Nd = 128;
        src = Wf2r; soff = (long)l * 65536; dst = f2T; doff = (long)l * 65536;
    }
    int ntile = Nd >> 5;
    int tk = t / ntile, tn = t % ntile;
    __shared__ u16 Ts[32][33];
    int rr = threadIdx.x >> 3, cc0 = (threadIdx.x & 7) * 4;
#pragma unroll
    for (int i = 0; i < 4; ++i) {
        long idx = soff + (long)(tk * 32 + rr) * Nd + tn * 32 + cc0 + i;
        Ts[rr][cc0 + i] = f2bf(ldin(src, idx, bf));
    }
    __syncthreads();
#pragma unroll
    for (int i = 0; i < 4; ++i) {
        long idx = doff + (long)(tn * 32 + rr) * Kd + tk * 32 + cc0 + i;
        dst[idx] = Ts[cc0 + i][rr];
    }
}

// ---------- LayerNorm: one wave per row; bf16 output ----------
__global__ __launch_bounds__(256) void ln_kernel(
    const float* __restrict__ h, const void* graw, const void* braw, long off,
    u16* __restrict__ out, const int* flagp) {
    int bf = *flagp;
    int row = blockIdx.x * 4 + (threadIdx.x >> 6);
    int lane = threadIdx.x & 63;
    const float* p = h + (size_t)row * Hq;
    float x0 = p[lane], x1 = p[lane + 64];
    float s = x0 + x1, s2 = x0 * x0 + x1 * x1;
#pragma unroll
    for (int o = 32; o; o >>= 1) {
        s += __shfl_xor(s, o);
        s2 += __shfl_xor(s2, o);
    }
    float mu = s * (1.0f / 128.0f);
    float var = fmaxf(s2 * (1.0f / 128.0f) - mu * mu, 0.0f);
    float rr = rsqrtf(var + 1e-5f);
    float g0 = ldin(graw, off + lane, bf), g1v = ldin(graw, off + lane + 64, bf);
    float b0 = ldin(braw, off + lane, bf), b1v = ldin(braw, off + lane + 64, bf);
    out[(size_t)row * Hq + lane]      = f2bf((x0 - mu) * rr * g0 + b0);
    out[(size_t)row * Hq + lane + 64] = f2bf((x1 - mu) * rr * g1v + b1v);
}

// ================== MFMA GEMM machinery ==================
// A: bf16 [M][K]; WT: bf16 [128][K] (N fixed 128); C: f32 [M][128] (+resid)
// block: 256 thr, tile 128(M)x128(N); wave quadrant 64x64; 16x16x32 MFMA
__global__ __launch_bounds__(256, 2) void mfma_gemm_kernel(
    const u16* __restrict__ A, const u16* __restrict__ WT,
    const void* __restrict__ braw, long bOff, float* __restrict__ C,
    int K, int resid, const int* flagp) {
    __shared__ __align__(16) u16 As[128][40];
    __shared__ __align__(16) u16 Bs[128][40];
    int tid = threadIdx.x;
    int m0 = blockIdx.x * 128;
    int wave = tid >> 6, lane = tid & 63;
    int wm = (wave >> 1) * 64, wn = (wave & 1) * 64;
    int q = lane >> 4, ln = lane & 15;
    f32x4 zero = {0.f, 0.f, 0.f, 0.f};
    f32x4 acc[4][4];
#pragma unroll
    for (int i = 0; i < 4; ++i)
#pragma unroll
        for (int j = 0; j < 4; ++j) acc[i][j] = zero;
    int sr = tid >> 1, sc = (tid & 1) * 16;
    const u16* Ap = A + (size_t)(m0 + sr) * K + sc;
    const u16* Bp = WT + (size_t)sr * K + sc;
    for (int k0 = 0; k0 < K; k0 += 32) {
        uint4 a0 = *(const uint4*)(Ap + k0);
        uint4 a1 = *(const uint4*)(Ap + k0 + 8);
        uint4 b0 = *(const uint4*)(Bp + k0);
        uint4 b1 = *(const uint4*)(Bp + k0 + 8);
        *(uint4*)&As[sr][sc] = a0; *(uint4*)&As[sr][sc + 8] = a1;
        *(uint4*)&Bs[sr][sc] = b0; *(uint4*)&Bs[sr][sc + 8] = b1;
        __syncthreads();
        short8 af[4], bfv[4];
#pragma unroll
        for (int t = 0; t < 4; ++t) {
            af[t]  = *(const short8*)&As[wm + t * 16 + ln][q * 8];
            bfv[t] = *(const short8*)&Bs[wn + t * 16 + ln][q * 8];
        }
#pragma unroll
        for (int ti = 0; ti < 4; ++ti)
#pragma unroll
            for (int tj = 0; tj < 4; ++tj)
                acc[ti][tj] = __builtin_amdgcn_mfma_f32_16x16x32_bf16(
                    af[ti], bfv[tj], acc[ti][tj], 0, 0, 0);
        __syncthreads();
    }
    int bf = *flagp;
#pragma unroll
    for (int tj = 0; tj < 4; ++tj) {
        int n = wn + tj * 16 + ln;
        float bias = ldin(braw, bOff + n, bf);
#pragma unroll
        for (int ti = 0; ti < 4; ++ti) {
#pragma unroll
            for (int r = 0; r < 4; ++r) {
                int m = m0 + wm + ti * 16 + q * 4 + r;
                float v = acc[ti][tj][r] + bias;
                float* dst = C + (size_t)m * 128 + n;
                if (resid) v += *dst;
                *dst = v;
            }
        }
    }
}

// QKV fused: blockIdx.y selects q/k/v; outputs f32
__global__ __launch_bounds__(256, 2) void qkv_mfma_kernel(
    const u16* __restrict__ A, const u16* __restrict__ qkvT_l,
    const void* bqr, const void* bkr, const void* bvr, long bOff,
    float* __restrict__ Qo, float* __restrict__ Ko, float* __restrict__ Vo,
    const int* flagp) {
    int sel = blockIdx.y;
    const u16* WT = qkvT_l + (size_t)sel * 16384;
    const void* braw = sel == 0 ? bqr : (sel == 1 ? bkr : bvr);
    float* C = sel == 0 ? Qo : (sel == 1 ? Ko : Vo);
    __shared__ __align__(16) u16 As[128][40];
    __shared__ __align__(16) u16 Bs[128][40];
    int tid = threadIdx.x;
    int m0 = blockIdx.x * 128;
    int wave = tid >> 6, lane = tid & 63;
    int wm = (wave >> 1) * 64, wn = (wave & 1) * 64;
    int q = lane >> 4, ln = lane & 15;
    f32x4 zero = {0.f, 0.f, 0.f, 0.f};
    f32x4 acc[4][4];
#pragma unroll
    for (int i = 0; i < 4; ++i)
#pragma unroll
        for (int j = 0; j < 4; ++j) acc[i][j] = zero;
    int sr = tid >> 1, sc = (tid & 1) * 16;
    const u16* Ap = A + (size_t)(m0 + sr) * 128 + sc;
    const u16* Bp = WT + (size_t)sr * 128 + sc;
#pragma unroll
    for (int k0 = 0; k0 < 128; k0 += 32) {
        uint4 a0 = *(const uint4*)(Ap + k0);
        uint4 a1 = *(const uint4*)(Ap + k0 + 8);
        uint4 b0 = *(const uint4*)(Bp + k0);
        uint4 b1 = *(const uint4*)(Bp + k0 + 8);
        *(uint4*)&As[sr][sc] = a0; *(uint4*)&As[sr][sc + 8] = a1;
        *(uint4*)&Bs[sr][sc] = b0; *(uint4*)&Bs[sr][sc + 8] = b1;
        __syncthreads();
        short8 af[4], bfv[4];
#pragma unroll
        for (int t = 0; t < 4; ++t) {
            af[t]  = *(const short8*)&As[wm + t * 16 + ln][q * 8];
            bfv[t] = *(const short8*)&Bs[wn + t * 16 + ln][q * 8];
        }
#pragma unroll
        for (int ti = 0; ti < 4; ++ti)
#pragma unroll
            for (int tj = 0; tj < 4; ++tj)
                acc[ti][tj] = __builtin_amdgcn_mfma_f32_16x16x32_bf16(
                    af[ti], bfv[tj], acc[ti][tj], 0, 0, 0);
        __syncthreads();
    }
    int bf = *flagp;
#pragma unroll
    for (int tj = 0; tj < 4; ++tj) {
        int n = wn + tj * 16 + ln;
        float bias = ldin(braw, bOff + n, bf);
#pragma unroll
        for (int ti = 0; ti < 4; ++ti)
#pragma unroll
            for (int r = 0; r < 4; ++r) {
                int m = m0 + wm + ti * 16 + q * 4 + r;
                C[(size_t)m * 128 + n] = acc[ti][tj][r] + bias;
            }
    }
}

// GLU-FF1: A[M][128] @ Wf1 -> ua*sigmoid(ub), out bf16 [M][512]
// block tile: 128(M) x 64(out-N); wave: 64m x 32n, a+b halves
__global__ __launch_bounds__(256, 2) void glu_mfma_kernel(
    const u16* __restrict__ A, const u16* __restrict__ f1T_l,
    const void* __restrict__ braw, long bOff, u16* __restrict__ Vout,
    const int* flagp) {
    __shared__ __align__(16) u16 As[128][40];
    __shared__ __align__(16) u16 Ba[64][40];
    __shared__ __align__(16) u16 Bb[64][40];
    int tid = threadIdx.x;
    int m0 = blockIdx.x * 128, n0 = blockIdx.y * 64;
    int wave = tid >> 6, lane = tid & 63;
    int wm = (wave >> 1) * 64, wn = (wave & 1) * 32;
    int q = lane >> 4, ln = lane & 15;
    f32x4 zero = {0.f, 0.f, 0.f, 0.f};
    f32x4 accA[4][2], accB[4][2];
#pragma unroll
    for (int i = 0; i < 4; ++i)
#pragma unroll
        for (int j = 0; j < 2; ++j) { accA[i][j] = zero; accB[i][j] = zero; }
    int sr = tid >> 1, sc = (tid & 1) * 16;
    const u16* Ap = A + (size_t)(m0 + sr) * 128 + sc;
    const u16* BpA = f1T_l + (size_t)(n0 + sr) * 128 + sc;            // rows n0..n0+63  (sr<64)
    const u16* BpB = f1T_l + (size_t)(512 + n0 + (sr - 64)) * 128 + sc; // rows 512+n0..  (sr>=64)
#pragma unroll
    for (int k0 = 0; k0 < 128; k0 += 32) {
        uint4 a0 = *(const uint4*)(Ap + k0);
        uint4 a1 = *(const uint4*)(Ap + k0 + 8);
        *(uint4*)&As[sr][sc] = a0; *(uint4*)&As[sr][sc + 8] = a1;
        if (sr < 64) {
            uint4 w0 = *(const uint4*)(BpA + k0);
            uint4 w1 = *(const uint4*)(BpA + k0 + 8);
            *(uint4*)&Ba[sr][sc] = w0; *(uint4*)&Ba[sr][sc + 8] = w1;
        } else {
            uint4 w0 = *(const uint4*)(BpB + k0);
            uint4 w1 = *(const uint4*)(BpB + k0 + 8);
            *(uint4*)&Bb[sr - 64][sc] = w0; *(uint4*)&Bb[sr - 64][sc + 8] = w1;
        }
        __syncthreads();
        short8 af[4], ba[2], bb[2];
#pragma unroll
        for (int t = 0; t < 4; ++t) af[t] = *(const short8*)&As[wm + t * 16 + ln][q * 8];
#pragma unroll
        for (int t = 0; t < 2; ++t) {
            ba[t] = *(const short8*)&Ba[wn + t * 16 + ln][q * 8];
            bb[t] = *(const short8*)&Bb[wn + t * 16 + ln][q * 8];
        }
#pragma unroll
        for (int ti = 0; ti < 4; ++ti)
#pragma unroll
            for (int tj = 0; tj < 2; ++tj) {
                accA[ti][tj] = __builtin_amdgcn_mfma_f32_16x16x32_bf16(
                    af[ti], ba[tj], accA[ti][tj], 0, 0, 0);
                accB[ti][tj] = __builtin_amdgcn_mfma_f32_16x16x32_bf16(
                    af[ti], bb[tj], accB[ti][tj], 0, 0, 0);
            }
        __syncthreads();
    }
    int bf = *flagp;
#pragma unroll
    for (int tj = 0; tj < 2; ++tj) {
        int n = n0 + wn + tj * 16 + ln;
        float biasA = ldin(braw, bOff + n, bf);
        float biasB = ldin(braw, bOff + 512 + n, bf);
#pragma unroll
        for (int ti = 0; ti < 4; ++ti)
#pragma unroll
            for (int r = 0; r < 4; ++r) {
                int m = m0 + wm + ti * 16 + q * 4 + r;
                float ua = accA[ti][tj][r] + biasA;
                float ub = accB[ti][tj][r] + biasB;
                Vout[(size_t)m * 512 + n] = f2bf(ua / (1.0f + __expf(-ub)));
            }
    }
}

// ---------- attention v2 (unchanged math); bf16 output ----------
__global__ __launch_bounds__(256) void attn_kernel(
    const float* __restrict__ Q, const float* __restrict__ Kg,
    const float* __restrict__ Vg, const unsigned char* __restrict__ bins,
    const unsigned int* __restrict__ mbits, const float* __restrict__ deL,
    const float* __restrict__ abL, u16* __restrict__ out) {
    __shared__ float4 Ks[Nq * 4];
    __shared__ float4 Vs[Nq * 4];
    int b = blockIdx.z, nh = blockIdx.y;
    int tid = threadIdx.x;
    const float* Kp = Kg + ((size_t)b * Nq) * Hq + nh * HDq;
    const float* Vp = Vg + ((size_t)b * Nq) * Hq + nh * HDq;
    for (int j = tid; j < Nq * 4; j += 256) {
        int k = j >> 2, c = j & 3;
        Ks[j] = *(const float4*)(Kp + (size_t)k * Hq + c * 4);
        Vs[j] = *(const float4*)(Vp + (size_t)k * Hq + c * 4);
    }
    __syncthreads();
    int wave = tid >> 6, lane = tid & 63;
    int q = blockIdx.x * 256 + wave * 64 + lane;
    float tbl = (lane < 50) ? deL[lane * NHq + nh] + abL[nh] : 0.0f;
    unsigned mwall = (lane < 16) ? mbits[b * 16 + lane] : 0u;
    const float* Qp = Q + ((size_t)(b * Nq + q)) * Hq + nh * HDq;
    float4 qa = *(const float4*)(Qp);
    float4 qb = *(const float4*)(Qp + 4);
    float4 qc = *(const float4*)(Qp + 8);
    float4 qd = *(const float4*)(Qp + 12);
    const unsigned char* brow = bins + ((size_t)(b * Nq + q)) * Nq;
    float o[16];
#pragma unroll
    for (int d = 0; d < 16; ++d) o[d] = 0.0f;
    float z = 0.0f;
    for (int k32 = 0; k32 < 16; ++k32) {
        unsigned w = (unsigned)__shfl((int)mwall, k32);
        if (w == 0xFFFFFFFFu) continue;
        const unsigned* b32p = (const unsigned*)(brow + k32 * 32);
#pragma unroll 2
        for (int kg = 0; kg < 8; ++kg) {
            unsigned bv4 = b32p[kg];
#pragma unroll
            for (int j = 0; j < 4; ++j) {
                if (!((w >> (kg * 4 + j)) & 1u)) {
                    int kk = k32 * 32 + kg * 4 + j;
                    float4 ka = Ks[kk * 4 + 0];
                    float4 kb = Ks[kk * 4 + 1];
                    float4 kc = Ks[kk * 4 + 2];
                    float4 kd = Ks[kk * 4 + 3];
                    float s0 = qa.x * ka.x + qa.y * ka.y + qa.z * ka.z + qa.w * ka.w;
                    float s1 = qb.x * kb.x + qb.y * kb.y + qb.z * kb.z + qb.w * kb.w;
                    float s2 = qc.x * kc.x + qc.y * kc.y + qc.z * kc.z + qc.w * kc.w;
                    float s3 = qd.x * kd.x + qd.y * kd.y + qd.z * kd.z + qd.w * kd.w;
                    float bias = __shfl(tbl, (int)((bv4 >> (8 * j)) & 0xFFu));
                    float s = ((s0 + s1) + (s2 + s3)) * 0.25f + bias;
                    float p = __expf(s);
                    z += p;
                    float4 va = Vs[kk * 4 + 0];
                    float4 vb = Vs[kk * 4 + 1];
                    float4 vc = Vs[kk * 4 + 2];
                    float4 vd = Vs[kk * 4 + 3];
                    o[0] += p * va.x;  o[1] += p * va.y;  o[2] += p * va.z;  o[3] += p * va.w;
                    o[4] += p * vb.x;  o[5] += p * vb.y;  o[6] += p * vb.z;  o[7] += p * vb.w;
                    o[8] += p * vc.x;  o[9] += p * vc.y;  o[10] += p * vc.z; o[11] += p * vc.w;
                    o[12] += p * vd.x; o[13] += p * vd.y; o[14] += p * vd.z; o[15] += p * vd.w;
                }
            }
        }
    }
    float r = 1.0f / fmaxf(z, 1e-35f);
    u16* op = out + ((size_t)(b * Nq + q)) * Hq + nh * HDq;
    unsigned pk[8];
#pragma unroll
    for (int i = 0; i < 8; ++i)
        pk[i] = (unsigned)f2bf(o[2 * i] * r) | ((unsigned)f2bf(o[2 * i + 1] * r) << 16);
    *(uint4*)(op)     = make_uint4(pk[0], pk[1], pk[2], pk[3]);
    *(uint4*)(op + 8) = make_uint4(pk[4], pk[5], pk[6], pk[7]);
}

// ---------- output ----------
__global__ void out_kernel(const float* __restrict__ h, void* out,
                           const int* flagp, int n) {
    int bf = *flagp;
    int i = blockIdx.x * 256 + threadIdx.x;
    if (i < n) {
        float v = h[i];
        if (bf) ((u16*)out)[i] = f2bf(v);
        else ((float*)out)[i] = v;
    }
}

extern "C" void kernel_launch(void* const* d_in, const int* in_sizes, int n_in,
                              void* d_out, int out_size, void* d_ws, size_t ws_size,
                              hipStream_t stream) {
    const void* x  = d_in[0];
    const void* dist = d_in[1];
    const void* mask = d_in[2];
    const void* Wq = d_in[3];  const void* bq = d_in[4];
    const void* Wk = d_in[5];  const void* bk = d_in[6];
    const void* Wv = d_in[7];  const void* bv = d_in[8];
    const void* Wo = d_in[9];  const void* bo = d_in[10];
    const void* de = d_in[11]; const void* ab = d_in[12];
    const void* g1 = d_in[13]; const void* b1 = d_in[14];
    const void* g2 = d_in[15]; const void* b2 = d_in[16];
    const void* Wf1 = d_in[17]; const void* bf1 = d_in[18];
    const void* Wf2 = d_in[19]; const void* bf2 = d_in[20];

    // workspace layout (bytes)
    char* ws = (char*)d_ws;
    const size_t OFF_DE   = 64;
    const size_t OFF_AB   = 5120;
    const size_t OFF_BINS = 8192;                    // 8,388,608
    const size_t OFF_MSK  = OFF_BINS + 8388608;      // 4096 reserved
    const size_t OFF_H    = OFF_MSK + 4096;          // f32 8,388,608
    const size_t OFF_QKV  = OFF_H + 8388608;         // Q,K,V f32 (3x8MB) | vglu u16 16MB
    const size_t OFF_HN   = OFF_QKV + 25165824;      // u16 4,194,304
    const size_t OFF_ATT  = OFF_HN + 4194304;        // u16 4,194,304
    const size_t OFF_WT   = OFF_ATT + 4194304;       // u16 1,572,864
    const size_t NEEDED   = OFF_WT + 1572864;
    if (ws_size < NEEDED) return;

    int* flag = (int*)ws;
    float* deF = (float*)(ws + OFF_DE);
    float* abF = (float*)(ws + OFF_AB);
    unsigned char* bins = (unsigned char*)(ws + OFF_BINS);
    unsigned* mbits = (unsigned*)(ws + OFF_MSK);
    float* h = (float*)(ws + OFF_H);
    float* Qb = (float*)(ws + OFF_QKV);
    float* Kb = Qb + 2097152;
    float* Vb = Qb + 2 * 2097152;
    u16* vglu = (u16*)(ws + OFF_QKV);
    u16* hn = (u16*)(ws + OFF_HN);
    u16* att = (u16*)(ws + OFF_ATT);
    u16* qkvT = (u16*)(ws + OFF_WT);                 // [L][3][128][128]
    u16* oT  = qkvT + 147456;                        // [L][128][128]
    u16* f1T = oT + 49152;                           // [L][1024][128]
    u16* f2T = f1T + 393216;                         // [L][128][512]

    detect_kernel<<<1, 256, 0, stream>>>(x, flag);
    conv_small_kernel<<<5, 256, 0, stream>>>(de, ab, deF, abF, flag);
    mask_prep_kernel<<<1, 256, 0, stream>>>(mask, mbits, Bq * Nq);
    bins_kernel<<<32768, 256, 0, stream>>>(dist, bins, flag, Bq * Nq * Nq);
    init_h_kernel<<<8192, 256, 0, stream>>>(x, h, flag, Mq * Hq);
    wtrans_kernel<<<768, 256, 0, stream>>>(Wq, Wk, Wv, Wo, Wf1, Wf2,
                                           qkvT, oT, f1T, f2T, flag);

    dim3 gqkv(128, 3);
    dim3 ga(2, NHq, Bq);
    dim3 gglu(128, 8);
    for (int l = 0; l < 3; ++l) {
        ln_kernel<<<4096, 256, 0, stream>>>(h, g1, b1, (long)l * Hq, hn, flag);
        qkv_mfma_kernel<<<gqkv, 256, 0, stream>>>(hn, qkvT + (size_t)l * 49152,
                                                  bq, bk, bv, (long)l * Hq,
                                                  Qb, Kb, Vb, flag);
        attn_kernel<<<ga, 256, 0, stream>>>(Qb, Kb, Vb, bins, mbits,
                                            deF + (long)l * 400, abF + (long)l * 8, att);
        mfma_gemm_kernel<<<128, 256, 0, stream>>>(att, oT + (size_t)l * 16384,
                                                  bo, (long)l * Hq, h, 128, 1, flag);
        ln_kernel<<<4096, 256, 0, stream>>>(h, g2, b2, (long)l * Hq, hn, flag);
        glu_mfma_kernel<<<gglu, 256, 0, stream>>>(hn, f1T + (size_t)l * 131072,
                                                  bf1, (long)l * 1024, vglu, flag);
        mfma_gemm_kernel<<<128, 256, 0, stream>>>(vglu, f2T + (size_t)l * 65536,
                                                  bf2, (long)l * Hq, h, 512, 1, flag);
    }
    out_kernel<<<8192, 256, 0, stream>>>(h, d_out, flag, Mq * Hq);
}

// Round 5
// 525.074 us; speedup vs baseline: 4.5734x; 1.3124x over previous
//
#include <hip/hip_runtime.h>
#include <stdint.h>

#define Bq 32
#define Nq 512
#define Hq 128
#define NHq 8
#define HDq 16
#define Mq (Bq * Nq)   // 16384

typedef unsigned short u16;
typedef __attribute__((ext_vector_type(8))) short short8;
typedef __attribute__((ext_vector_type(8))) _Float16 half8;
typedef __attribute__((ext_vector_type(2))) __fp16 fp16x2;
typedef __attribute__((ext_vector_type(4))) float f32x4;

// ---------- dtype-flex helpers (flag: 1 = inputs are bf16, 0 = f32) ----------
__device__ __forceinline__ float bf2f(u16 v) {
    return __uint_as_float(((unsigned int)v) << 16);
}
__device__ __forceinline__ float ldin(const void* p, long idx, int bf) {
    if (bf) return bf2f(((const u16*)p)[idx]);
    return ((const float*)p)[idx];
}
__device__ __forceinline__ u16 f2bf(float v) {   // RNE
    unsigned int u = __float_as_uint(v);
    return (u16)((u + 0x7FFFu + ((u >> 16) & 1u)) >> 16);
}
__device__ __forceinline__ u16 f2h(float v) {    // f32 -> f16 bits (RNE)
    _Float16 h = (_Float16)v;
    return *(u16*)&h;
}
__device__ __forceinline__ unsigned pk2h(float a, float b) {  // packed f16 pair bits
    fp16x2 c = __builtin_amdgcn_cvt_pkrtz(a, b);
    return *(unsigned*)&c;
}

// ---------- dtype detection ----------
__global__ void detect_kernel(const void* xraw, int* flag) {
    __shared__ int cnt;
    if (threadIdx.x == 0) cnt = 0;
    __syncthreads();
    const u16* u = (const u16*)xraw;
    int good = 0;
    for (int i = threadIdx.x; i < 1024; i += 256) {
        u16 v = u[i];
        int e = (v >> 7) & 0xFF;
        if (v == 0 || (e >= 90 && e <= 141)) good++;
    }
    atomicAdd(&cnt, good);
    __syncthreads();
    if (threadIdx.x == 0) *flag = (cnt >= 900) ? 1 : 0;
}

// ---------- mask prep -> bit-words (1 = masked) ----------
__global__ void mask_prep_kernel(const void* mraw, unsigned* mbits, int n) {
    __shared__ int orA, orB, orC, orD;
    if (threadIdx.x == 0) { orA = 0; orB = 0; orC = 0; orD = 0; }
    __syncthreads();
    const unsigned char* p = (const unsigned char*)mraw;
    int a = 0, b = 0, c = 0, d = 0;
    for (int i = threadIdx.x; i < n; i += 256) {
        int v = p[i];
        a |= v & 0xFE;
        if ((i & 3) == 1) b |= v;
        if (i & 3) c |= v;
        if (i & 4) d |= v;
    }
    if (a) atomicOr(&orA, 1);
    if (b) atomicOr(&orB, 1);
    if (c) atomicOr(&orC, 1);
    if (d) atomicOr(&orD, 1);
    __syncthreads();
    int mode;  // 0 bool8, 1 int32, 2 int64, 3 bf16, 4 f32
    if (orA) mode = orB ? 3 : 4;
    else if (orC) mode = 0;
    else mode = orD ? 1 : 2;
    for (int wI = threadIdx.x; wI < n / 32; wI += 256) {
        unsigned word = 0;
        for (int j = 0; j < 32; ++j) {
            int i = wI * 32 + j;
            int v;
            switch (mode) {
                case 0: v = p[i]; break;
                case 1: v = ((const int*)p)[i]; break;
                case 2: v = (int)((const long long*)p)[i]; break;
                case 3: v = ((const u16*)p)[i] != 0; break;
                default: v = (((const float*)p)[i] != 0.0f); break;
            }
            if (v) word |= 1u << j;
        }
        mbits[wI] = word;
    }
}

// ---------- small converts ----------
__global__ void conv_small_kernel(const void* de, const void* ab,
                                  float* deo, float* abo, const int* flagp) {
    int bf = *flagp;
    int i = blockIdx.x * 256 + threadIdx.x;
    if (i < 1200) deo[i] = ldin(de, i, bf);
    if (i < 24) abo[i] = ldin(ab, i, bf);
}

// ---------- bins ----------
__global__ void bins_kernel(const void* dist, unsigned char* bins,
                            const int* flagp, int n) {
    int bf = *flagp;
    int i = blockIdx.x * 256 + threadIdx.x;
    if (i < n) {
        float d = ldin(dist, i, bf);
        int v = (int)(d * 10.0f);
        v = v < 0 ? 0 : (v > 49 ? 49 : v);
        bins[i] = (unsigned char)v;
    }
}

// ---------- h init ----------
__global__ void init_h_kernel(const void* x, float* h, const int* flagp, int n) {
    int i = blockIdx.x * 256 + threadIdx.x;
    if (i < n) h[i] = ldin(x, i, *flagp);
}

// ---------- weight transpose: W[K][N] -> WT[N][K] bf16 ----------
__global__ __launch_bounds__(256) void wtrans_kernel(
    const void* Wqr, const void* Wkr, const void* Wvr, const void* Wor,
    const void* Wf1r, const void* Wf2r,
    u16* qkvT, u16* oT, u16* f1T, u16* f2T, const int* flagp) {
    int bf = *flagp;
    int bid = blockIdx.x;
    int l = bid >> 8, r = bid & 255;
    const void* src; u16* dst; long soff, doff; int Kd, Nd, t;
    if (r < 64) {
        int mat = r >> 4; t = r & 15; Kd = 128; Nd = 128;
        soff = (long)l * 16384;
        if (mat == 0)      { src = Wqr; dst = qkvT; doff = (long)l * 49152; }
        else if (mat == 1) { src = Wkr; dst = qkvT; doff = (long)l * 49152 + 16384; }
        else if (mat == 2) { src = Wvr; dst = qkvT; doff = (long)l * 49152 + 32768; }
        else               { src = Wor; dst = oT;   doff = (long)l * 16384; }
    } else if (r < 192) {
        t = r - 64; Kd = 128; Nd = 1024;
        src = Wf1r; soff = (long)l * 131072; dst = f1T; doff = (long)l * 131072;
    } else {
        t = r - 192; Kd = 512; Nd = 128;
        src = Wf2r; soff = (long)l * 65536; dst = f2T; doff = (long)l * 65536;
    }
    int ntile = Nd >> 5;
    int tk = t / ntile, tn = t % ntile;
    __shared__ u16 Ts[32][33];
    int rr = threadIdx.x >> 3, cc0 = (threadIdx.x & 7) * 4;
#pragma unroll
    for (int i = 0; i < 4; ++i) {
        long idx = soff + (long)(tk * 32 + rr) * Nd + tn * 32 + cc0 + i;
        Ts[rr][cc0 + i] = f2bf(ldin(src, idx, bf));
    }
    __syncthreads();
#pragma unroll
    for (int i = 0; i < 4; ++i) {
        long idx = doff + (long)(tn * 32 + rr) * Kd + tk * 32 + cc0 + i;
        dst[idx] = Ts[cc0 + i][rr];
    }
}

// ---------- LayerNorm: one wave per row; bf16 output ----------
__global__ __launch_bounds__(256) void ln_kernel(
    const float* __restrict__ h, const void* graw, const void* braw, long off,
    u16* __restrict__ out, const int* flagp) {
    int bf = *flagp;
    int row = blockIdx.x * 4 + (threadIdx.x >> 6);
    int lane = threadIdx.x & 63;
    const float* p = h + (size_t)row * Hq;
    float x0 = p[lane], x1 = p[lane + 64];
    float s = x0 + x1, s2 = x0 * x0 + x1 * x1;
#pragma unroll
    for (int o = 32; o; o >>= 1) {
        s += __shfl_xor(s, o);
        s2 += __shfl_xor(s2, o);
    }
    float mu = s * (1.0f / 128.0f);
    float var = fmaxf(s2 * (1.0f / 128.0f) - mu * mu, 0.0f);
    float rr = rsqrtf(var + 1e-5f);
    float g0 = ldin(graw, off + lane, bf), g1v = ldin(graw, off + lane + 64, bf);
    float b0 = ldin(braw, off + lane, bf), b1v = ldin(braw, off + lane + 64, bf);
    out[(size_t)row * Hq + lane]      = f2bf((x0 - mu) * rr * g0 + b0);
    out[(size_t)row * Hq + lane + 64] = f2bf((x1 - mu) * rr * g1v + b1v);
}

// ================== MFMA GEMM: A bf16 [M][K] @ WT bf16 [128][K] -> f32 (+resid) =====
__global__ __launch_bounds__(256, 2) void mfma_gemm_kernel(
    const u16* __restrict__ A, const u16* __restrict__ WT,
    const void* __restrict__ braw, long bOff, float* __restrict__ C,
    int K, int resid, const int* flagp) {
    __shared__ __align__(16) u16 As[128][40];
    __shared__ __align__(16) u16 Bs[128][40];
    int tid = threadIdx.x;
    int m0 = blockIdx.x * 128;
    int wave = tid >> 6, lane = tid & 63;
    int wm = (wave >> 1) * 64, wn = (wave & 1) * 64;
    int q = lane >> 4, ln = lane & 15;
    f32x4 zero = {0.f, 0.f, 0.f, 0.f};
    f32x4 acc[4][4];
#pragma unroll
    for (int i = 0; i < 4; ++i)
#pragma unroll
        for (int j = 0; j < 4; ++j) acc[i][j] = zero;
    int sr = tid >> 1, sc = (tid & 1) * 16;
    const u16* Ap = A + (size_t)(m0 + sr) * K + sc;
    const u16* Bp = WT + (size_t)sr * K + sc;
    for (int k0 = 0; k0 < K; k0 += 32) {
        uint4 a0 = *(const uint4*)(Ap + k0);
        uint4 a1 = *(const uint4*)(Ap + k0 + 8);
        uint4 b0 = *(const uint4*)(Bp + k0);
        uint4 b1 = *(const uint4*)(Bp + k0 + 8);
        *(uint4*)&As[sr][sc] = a0; *(uint4*)&As[sr][sc + 8] = a1;
        *(uint4*)&Bs[sr][sc] = b0; *(uint4*)&Bs[sr][sc + 8] = b1;
        __syncthreads();
        short8 af[4], bfv[4];
#pragma unroll
        for (int t = 0; t < 4; ++t) {
            af[t]  = *(const short8*)&As[wm + t * 16 + ln][q * 8];
            bfv[t] = *(const short8*)&Bs[wn + t * 16 + ln][q * 8];
        }
#pragma unroll
        for (int ti = 0; ti < 4; ++ti)
#pragma unroll
            for (int tj = 0; tj < 4; ++tj)
                acc[ti][tj] = __builtin_amdgcn_mfma_f32_16x16x32_bf16(
                    af[ti], bfv[tj], acc[ti][tj], 0, 0, 0);
        __syncthreads();
    }
    int bf = *flagp;
#pragma unroll
    for (int tj = 0; tj < 4; ++tj) {
        int n = wn + tj * 16 + ln;
        float bias = ldin(braw, bOff + n, bf);
#pragma unroll
        for (int ti = 0; ti < 4; ++ti) {
#pragma unroll
            for (int r = 0; r < 4; ++r) {
                int m = m0 + wm + ti * 16 + q * 4 + r;
                float v = acc[ti][tj][r] + bias;
                float* dst = C + (size_t)m * 128 + n;
                if (resid) v += *dst;
                *dst = v;
            }
        }
    }
}

// QKV fused: outputs f16 bits; Q pre-scaled by 0.25
__global__ __launch_bounds__(256, 2) void qkv_mfma_kernel(
    const u16* __restrict__ A, const u16* __restrict__ qkvT_l,
    const void* bqr, const void* bkr, const void* bvr, long bOff,
    u16* __restrict__ Qo, u16* __restrict__ Ko, u16* __restrict__ Vo,
    const int* flagp) {
    int sel = blockIdx.y;
    const u16* WT = qkvT_l + (size_t)sel * 16384;
    const void* braw = sel == 0 ? bqr : (sel == 1 ? bkr : bvr);
    u16* C = sel == 0 ? Qo : (sel == 1 ? Ko : Vo);
    float scale = sel == 0 ? 0.25f : 1.0f;
    __shared__ __align__(16) u16 As[128][40];
    __shared__ __align__(16) u16 Bs[128][40];
    int tid = threadIdx.x;
    int m0 = blockIdx.x * 128;
    int wave = tid >> 6, lane = tid & 63;
    int wm = (wave >> 1) * 64, wn = (wave & 1) * 64;
    int q = lane >> 4, ln = lane & 15;
    f32x4 zero = {0.f, 0.f, 0.f, 0.f};
    f32x4 acc[4][4];
#pragma unroll
    for (int i = 0; i < 4; ++i)
#pragma unroll
        for (int j = 0; j < 4; ++j) acc[i][j] = zero;
    int sr = tid >> 1, sc = (tid & 1) * 16;
    const u16* Ap = A + (size_t)(m0 + sr) * 128 + sc;
    const u16* Bp = WT + (size_t)sr * 128 + sc;
#pragma unroll
    for (int k0 = 0; k0 < 128; k0 += 32) {
        uint4 a0 = *(const uint4*)(Ap + k0);
        uint4 a1 = *(const uint4*)(Ap + k0 + 8);
        uint4 b0 = *(const uint4*)(Bp + k0);
        uint4 b1 = *(const uint4*)(Bp + k0 + 8);
        *(uint4*)&As[sr][sc] = a0; *(uint4*)&As[sr][sc + 8] = a1;
        *(uint4*)&Bs[sr][sc] = b0; *(uint4*)&Bs[sr][sc + 8] = b1;
        __syncthreads();
        short8 af[4], bfv[4];
#pragma unroll
        for (int t = 0; t < 4; ++t) {
            af[t]  = *(const short8*)&As[wm + t * 16 + ln][q * 8];
            bfv[t] = *(const short8*)&Bs[wn + t * 16 + ln][q * 8];
        }
#pragma unroll
        for (int ti = 0; ti < 4; ++ti)
#pragma unroll
            for (int tj = 0; tj < 4; ++tj)
                acc[ti][tj] = __builtin_amdgcn_mfma_f32_16x16x32_bf16(
                    af[ti], bfv[tj], acc[ti][tj], 0, 0, 0);
        __syncthreads();
    }
    int bf = *flagp;
#pragma unroll
    for (int tj = 0; tj < 4; ++tj) {
        int n = wn + tj * 16 + ln;
        float bias = ldin(braw, bOff + n, bf);
#pragma unroll
        for (int ti = 0; ti < 4; ++ti)
#pragma unroll
            for (int r = 0; r < 4; ++r) {
                int m = m0 + wm + ti * 16 + q * 4 + r;
                C[(size_t)m * 128 + n] = f2h((acc[ti][tj][r] + bias) * scale);
            }
    }
}

// GLU-FF1 (unchanged)
__global__ __launch_bounds__(256, 2) void glu_mfma_kernel(
    const u16* __restrict__ A, const u16* __restrict__ f1T_l,
    const void* __restrict__ braw, long bOff, u16* __restrict__ Vout,
    const int* flagp) {
    __shared__ __align__(16) u16 As[128][40];
    __shared__ __align__(16) u16 Ba[64][40];
    __shared__ __align__(16) u16 Bb[64][40];
    int tid = threadIdx.x;
    int m0 = blockIdx.x * 128, n0 = blockIdx.y * 64;
    int wave = tid >> 6, lane = tid & 63;
    int wm = (wave >> 1) * 64, wn = (wave & 1) * 32;
    int q = lane >> 4, ln = lane & 15;
    f32x4 zero = {0.f, 0.f, 0.f, 0.f};
    f32x4 accA[4][2], accB[4][2];
#pragma unroll
    for (int i = 0; i < 4; ++i)
#pragma unroll
        for (int j = 0; j < 2; ++j) { accA[i][j] = zero; accB[i][j] = zero; }
    int sr = tid >> 1, sc = (tid & 1) * 16;
    const u16* Ap = A + (size_t)(m0 + sr) * 128 + sc;
    const u16* BpA = f1T_l + (size_t)(n0 + sr) * 128 + sc;
    const u16* BpB = f1T_l + (size_t)(512 + n0 + (sr - 64)) * 128 + sc;
#pragma unroll
    for (int k0 = 0; k0 < 128; k0 += 32) {
        uint4 a0 = *(const uint4*)(Ap + k0);
        uint4 a1 = *(const uint4*)(Ap + k0 + 8);
        *(uint4*)&As[sr][sc] = a0; *(uint4*)&As[sr][sc + 8] = a1;
        if (sr < 64) {
            uint4 w0 = *(const uint4*)(BpA + k0);
            uint4 w1 = *(const uint4*)(BpA + k0 + 8);
            *(uint4*)&Ba[sr][sc] = w0; *(uint4*)&Ba[sr][sc + 8] = w1;
        } else {
            uint4 w0 = *(const uint4*)(BpB + k0);
            uint4 w1 = *(const uint4*)(BpB + k0 + 8);
            *(uint4*)&Bb[sr - 64][sc] = w0; *(uint4*)&Bb[sr - 64][sc + 8] = w1;
        }
        __syncthreads();
        short8 af[4], ba[2], bb[2];
#pragma unroll
        for (int t = 0; t < 4; ++t) af[t] = *(const short8*)&As[wm + t * 16 + ln][q * 8];
#pragma unroll
        for (int t = 0; t < 2; ++t) {
            ba[t] = *(const short8*)&Ba[wn + t * 16 + ln][q * 8];
            bb[t] = *(const short8*)&Bb[wn + t * 16 + ln][q * 8];
        }
#pragma unroll
        for (int ti = 0; ti < 4; ++ti)
#pragma unroll
            for (int tj = 0; tj < 2; ++tj) {
                accA[ti][tj] = __builtin_amdgcn_mfma_f32_16x16x32_bf16(
                    af[ti], ba[tj], accA[ti][tj], 0, 0, 0);
                accB[ti][tj] = __builtin_amdgcn_mfma_f32_16x16x32_bf16(
                    af[ti], bb[tj], accB[ti][tj], 0, 0, 0);
            }
        __syncthreads();
    }
    int bf = *flagp;
#pragma unroll
    for (int tj = 0; tj < 2; ++tj) {
        int n = n0 + wn + tj * 16 + ln;
        float biasA = ldin(braw, bOff + n, bf);
        float biasB = ldin(braw, bOff + 512 + n, bf);
#pragma unroll
        for (int ti = 0; ti < 4; ++ti)
#pragma unroll
            for (int r = 0; r < 4; ++r) {
                int m = m0 + wm + ti * 16 + q * 4 + r;
                float ua = accA[ti][tj][r] + biasA;
                float ub = accB[ti][tj][r] + biasB;
                Vout[(size_t)m * 512 + n] = f2bf(ua / (1.0f + __expf(-ub)));
            }
    }
}

// ================== attention v3: full-MFMA (S^T feed trick) ==================
// grid 1024 = swizzled (b, nh, qq); block 128 q, 4 waves x 32 q (2 q-16-tiles).
// S^T = K Q^T via mfma_f32_16x16x32_f16 (d padded 32); C-layout of S^T gives
// lane(quad,ln) -> (k=quad*4+r, q=ln).  P packed f16 via wave-private LDS
// (write b64 C-layout / read b128 A-layout; same-wave DS ops are in-order).
// O = P V via second MFMA chain; z in f32; fixed-shift softmax; masked -> p=0.
__global__ __launch_bounds__(256) void attn_kernel(
    const u16* __restrict__ Qh, const u16* __restrict__ Kh,
    const u16* __restrict__ Vh, const unsigned char* __restrict__ bins,
    const unsigned int* __restrict__ mbits, const float* __restrict__ deL,
    const float* __restrict__ abL, u16* __restrict__ out) {
    // de-swizzle: heads of one (b,qq) share id%8 -> same XCD L2 for bins
    int id = blockIdx.x;
    int c = id & 7, t5 = id >> 3;
    int nh = t5 & 7;
    int pair = ((t5 >> 3) << 3) | c;
    int b = pair >> 2, qq = pair & 3;

    __shared__ __align__(16) u16 Ks[512 * 24];   // rows 48B: 16 f16 + 8 pad
    __shared__ __align__(16) u16 VT[16 * 520];   // V^T rows 520 f16
    __shared__ __align__(16) u16 Pl[4 * 16 * 40];// per-wave P tile 16x(32+8)

    int tid = threadIdx.x;
    const u16* Kp = Kh + (size_t)(b * Nq) * Hq + nh * HDq;
    const u16* Vp = Vh + (size_t)(b * Nq) * Hq + nh * HDq;
    for (int r = tid; r < Nq; r += 256) {
        uint4 k0 = *(const uint4*)(Kp + (size_t)r * Hq);
        uint4 k1 = *(const uint4*)(Kp + (size_t)r * Hq + 8);
        *(uint4*)&Ks[r * 24]     = k0;
        *(uint4*)&Ks[r * 24 + 8] = k1;
        uint4 v0 = *(const uint4*)(Vp + (size_t)r * Hq);
        uint4 v1 = *(const uint4*)(Vp + (size_t)r * Hq + 8);
        u16 vv[16];
        *(uint4*)&vv[0] = v0; *(uint4*)&vv[8] = v1;
#pragma unroll
        for (int d = 0; d < 16; ++d) VT[d * 520 + r] = vv[d];
    }
    __syncthreads();

    int wave = tid >> 6, lane = tid & 63;
    int quad = lane >> 4, ln = lane & 15;
    int q0w = qq * 128 + wave * 32;

    float tbl = (lane < 50) ? deL[lane * NHq + nh] + abL[nh] : 0.0f;
    unsigned mwall = (lane < 16) ? mbits[b * 16 + lane] : 0u;

    // hoisted Q B-frags (quads 2,3 supply the zero d-padding)
    half8 qf[2];
#pragma unroll
    for (int t = 0; t < 2; ++t) {
        uint4 qv = {0, 0, 0, 0};
        if (quad < 2)
            qv = *(const uint4*)(Qh + (size_t)(b * Nq + q0w + t * 16 + ln) * Hq
                                 + nh * HDq + quad * 8);
        qf[t] = *(half8*)&qv;
    }

    f32x4 zero = {0.f, 0.f, 0.f, 0.f};
    f32x4 acc[2] = {zero, zero};
    float zp[2] = {0.f, 0.f};
    _Float16* Pw = (_Float16*)&Pl[wave * 16 * 40];
    const unsigned char* binsB = bins + (size_t)b * Nq * Nq;
    const _Float16* KsH = (const _Float16*)Ks;
    const _Float16* VTH = (const _Float16*)VT;

    for (int kt = 0; kt < 16; ++kt) {
        int k0 = kt * 32;
        unsigned w = (unsigned)__shfl((int)mwall, kt);
        half8 vb = *(const half8*)(VTH + ln * 520 + k0 + quad * 8);
        half8 ka0 = {}, ka1 = {};
        if (quad < 2) {
            ka0 = *(const half8*)(KsH + (size_t)(k0 + ln) * 24 + quad * 8);
            ka1 = *(const half8*)(KsH + (size_t)(k0 + 16 + ln) * 24 + quad * 8);
        }
#pragma unroll
        for (int t = 0; t < 2; ++t) {
            int q = q0w + t * 16 + ln;
            const unsigned char* brow = binsB + (size_t)q * Nq + k0;
            unsigned bw0 = *(const unsigned*)(brow + quad * 4);
            unsigned bw1 = *(const unsigned*)(brow + 16 + quad * 4);
            f32x4 s0 = __builtin_amdgcn_mfma_f32_16x16x32_f16(ka0, qf[t], zero, 0, 0, 0);
            f32x4 s1 = __builtin_amdgcn_mfma_f32_16x16x32_f16(ka1, qf[t], zero, 0, 0, 0);
            float p[8];
#pragma unroll
            for (int r = 0; r < 4; ++r) {
                float sc = s0[r] + __shfl(tbl, (int)((bw0 >> (8 * r)) & 0xFFu));
                bool m = (w >> (quad * 4 + r)) & 1u;
                p[r] = m ? 0.0f : __expf(sc);
            }
#pragma unroll
            for (int r = 0; r < 4; ++r) {
                float sc = s1[r] + __shfl(tbl, (int)((bw1 >> (8 * r)) & 0xFFu));
                bool m = (w >> (16 + quad * 4 + r)) & 1u;
                p[4 + r] = m ? 0.0f : __expf(sc);
            }
            zp[t] += ((p[0] + p[1]) + (p[2] + p[3])) +
                     ((p[4] + p[5]) + (p[6] + p[7]));
            uint2 w0, w1;
            w0.x = pk2h(p[0], p[1]); w0.y = pk2h(p[2], p[3]);
            w1.x = pk2h(p[4], p[5]); w1.y = pk2h(p[6], p[7]);
            *(uint2*)(Pw + ln * 40 + quad * 4)      = w0;   // sub0: k=quad*4+r
            *(uint2*)(Pw + ln * 40 + 16 + quad * 4) = w1;   // sub1: k=16+quad*4+r
            half8 pa = *(const half8*)(Pw + ln * 40 + quad * 8); // A[m=ln][k=quad*8+j]
            acc[t] = __builtin_amdgcn_mfma_f32_16x16x32_f16(pa, vb, acc[t], 0, 0, 0);
        }
    }
#pragma unroll
    for (int t = 0; t < 2; ++t) {
        zp[t] += __shfl_xor(zp[t], 16);
        zp[t] += __shfl_xor(zp[t], 32);
    }
#pragma unroll
    for (int t = 0; t < 2; ++t) {
#pragma unroll
        for (int r = 0; r < 4; ++r) {
            float zz = __shfl(zp[t], quad * 4 + r);
            float val = acc[t][r] / fmaxf(zz, 1e-35f);
            int qrow = q0w + t * 16 + quad * 4 + r;
            out[(size_t)(b * Nq + qrow) * Hq + nh * HDq + ln] = f2bf(val);
        }
    }
}

// ---------- output ----------
__global__ void out_kernel(const float* __restrict__ h, void* out,
                           const int* flagp, int n) {
    int bf = *flagp;
    int i = blockIdx.x * 256 + threadIdx.x;
    if (i < n) {
        float v = h[i];
        if (bf) ((u16*)out)[i] = f2bf(v);
        else ((float*)out)[i] = v;
    }
}

extern "C" void kernel_launch(void* const* d_in, const int* in_sizes, int n_in,
                              void* d_out, int out_size, void* d_ws, size_t ws_size,
                              hipStream_t stream) {
    const void* x  = d_in[0];
    const void* dist = d_in[1];
    const void* mask = d_in[2];
    const void* Wq = d_in[3];  const void* bq = d_in[4];
    const void* Wk = d_in[5];  const void* bk = d_in[6];
    const void* Wv = d_in[7];  const void* bv = d_in[8];
    const void* Wo = d_in[9];  const void* bo = d_in[10];
    const void* de = d_in[11]; const void* ab = d_in[12];
    const void* g1 = d_in[13]; const void* b1 = d_in[14];
    const void* g2 = d_in[15]; const void* b2 = d_in[16];
    const void* Wf1 = d_in[17]; const void* bf1 = d_in[18];
    const void* Wf2 = d_in[19]; const void* bf2 = d_in[20];

    char* ws = (char*)d_ws;
    const size_t OFF_DE   = 64;
    const size_t OFF_AB   = 5120;
    const size_t OFF_BINS = 8192;                    // 8,388,608
    const size_t OFF_MSK  = OFF_BINS + 8388608;      // 4096
    const size_t OFF_H    = OFF_MSK + 4096;          // f32 8,388,608
    const size_t OFF_QKV  = OFF_H + 8388608;         // Qh,Kh,Vh f16 (3x4MB) | vglu u16 16MB
    const size_t OFF_HN   = OFF_QKV + 25165824;      // u16 4,194,304
    const size_t OFF_ATT  = OFF_HN + 4194304;        // u16 4,194,304
    const size_t OFF_WT   = OFF_ATT + 4194304;       // u16 1,572,864
    const size_t NEEDED   = OFF_WT + 1572864;
    if (ws_size < NEEDED) return;

    int* flag = (int*)ws;
    float* deF = (float*)(ws + OFF_DE);
    float* abF = (float*)(ws + OFF_AB);
    unsigned char* bins = (unsigned char*)(ws + OFF_BINS);
    unsigned* mbits = (unsigned*)(ws + OFF_MSK);
    float* h = (float*)(ws + OFF_H);
    u16* Qh = (u16*)(ws + OFF_QKV);
    u16* Kh = Qh + 2097152;
    u16* Vh = Qh + 2 * 2097152;
    u16* vglu = (u16*)(ws + OFF_QKV);
    u16* hn = (u16*)(ws + OFF_HN);
    u16* att = (u16*)(ws + OFF_ATT);
    u16* qkvT = (u16*)(ws + OFF_WT);
    u16* oT  = qkvT + 147456;
    u16* f1T = oT + 49152;
    u16* f2T = f1T + 393216;

    detect_kernel<<<1, 256, 0, stream>>>(x, flag);
    conv_small_kernel<<<5, 256, 0, stream>>>(de, ab, deF, abF, flag);
    mask_prep_kernel<<<1, 256, 0, stream>>>(mask, mbits, Bq * Nq);
    bins_kernel<<<32768, 256, 0, stream>>>(dist, bins, flag, Bq * Nq * Nq);
    init_h_kernel<<<8192, 256, 0, stream>>>(x, h, flag, Mq * Hq);
    wtrans_kernel<<<768, 256, 0, stream>>>(Wq, Wk, Wv, Wo, Wf1, Wf2,
                                           qkvT, oT, f1T, f2T, flag);

    dim3 gqkv(128, 3);
    dim3 gglu(128, 8);
    for (int l = 0; l < 3; ++l) {
        ln_kernel<<<4096, 256, 0, stream>>>(h, g1, b1, (long)l * Hq, hn, flag);
        qkv_mfma_kernel<<<gqkv, 256, 0, stream>>>(hn, qkvT + (size_t)l * 49152,
                                                  bq, bk, bv, (long)l * Hq,
                                                  Qh, Kh, Vh, flag);
        attn_kernel<<<1024, 256, 0, stream>>>(Qh, Kh, Vh, bins, mbits,
                                              deF + (long)l * 400, abF + (long)l * 8, att);
        mfma_gemm_kernel<<<128, 256, 0, stream>>>(att, oT + (size_t)l * 16384,
                                                  bo, (long)l * Hq, h, 128, 1, flag);
        ln_kernel<<<4096, 256, 0, stream>>>(h, g2, b2, (long)l * Hq, hn, flag);
        glu_mfma_kernel<<<gglu, 256, 0, stream>>>(hn, f1T + (size_t)l * 131072,
                                                  bf1, (long)l * 1024, vglu, flag);
        mfma_gemm_kernel<<<128, 256, 0, stream>>>(vglu, f2T + (size_t)l * 65536,
                                                  bf2, (long)l * Hq, h, 512, 1, flag);
    }
    out_kernel<<<8192, 256, 0, stream>>>(h, d_out, flag, Mq * Hq);
}

// Round 6
// 469.266 us; speedup vs baseline: 5.1173x; 1.1189x over previous
//
#include <hip/hip_runtime.h>
#include <stdint.h>

#define Bq 32
#define Nq 512
#define Hq 128
#define NHq 8
#define HDq 16
#define Mq (Bq * Nq)   // 16384

typedef unsigned short u16;
typedef __attribute__((ext_vector_type(8))) short short8;
typedef __attribute__((ext_vector_type(8))) _Float16 half8;
typedef __attribute__((ext_vector_type(2))) __fp16 fp16x2;
typedef __attribute__((ext_vector_type(4))) float f32x4;

// ---------- dtype-flex helpers (flag: 1 = inputs are bf16, 0 = f32) ----------
__device__ __forceinline__ float bf2f(u16 v) {
    return __uint_as_float(((unsigned int)v) << 16);
}
__device__ __forceinline__ float ldin(const void* p, long idx, int bf) {
    if (bf) return bf2f(((const u16*)p)[idx]);
    return ((const float*)p)[idx];
}
__device__ __forceinline__ u16 f2bf(float v) {   // RNE
    unsigned int u = __float_as_uint(v);
    return (u16)((u + 0x7FFFu + ((u >> 16) & 1u)) >> 16);
}
__device__ __forceinline__ u16 f2h(float v) {    // f32 -> f16 bits (RNE)
    _Float16 h = (_Float16)v;
    return *(u16*)&h;
}
__device__ __forceinline__ unsigned pk2h(float a, float b) {  // packed f16 pair bits
    fp16x2 c = __builtin_amdgcn_cvt_pkrtz(a, b);
    return *(unsigned*)&c;
}

// ---------- merged prep: dtype detect + small converts + mask bit-words ----------
__global__ void prep_kernel(const void* xraw, const void* de, const void* ab,
                            const void* mraw, int* flag, float* deo, float* abo,
                            unsigned* mbits, int n) {
    __shared__ int cnt, orA, orB, orC, orD;
    int tid = threadIdx.x;
    if (tid == 0) { cnt = 0; orA = 0; orB = 0; orC = 0; orD = 0; }
    __syncthreads();
    // dtype detect on x
    const u16* u = (const u16*)xraw;
    int good = 0;
    for (int i = tid; i < 1024; i += 256) {
        u16 v = u[i];
        int e = (v >> 7) & 0xFF;
        if (v == 0 || (e >= 90 && e <= 141)) good++;
    }
    atomicAdd(&cnt, good);
    // mask encoding scan
    const unsigned char* p = (const unsigned char*)mraw;
    int a = 0, b = 0, c = 0, d = 0;
    for (int i = tid; i < n; i += 256) {
        int v = p[i];
        a |= v & 0xFE;
        if ((i & 3) == 1) b |= v;
        if (i & 3) c |= v;
        if (i & 4) d |= v;
    }
    if (a) atomicOr(&orA, 1);
    if (b) atomicOr(&orB, 1);
    if (c) atomicOr(&orC, 1);
    if (d) atomicOr(&orD, 1);
    __syncthreads();
    int bf = (cnt >= 900);
    if (tid == 0) *flag = bf;
    int mode;  // 0 bool8, 1 int32, 2 int64, 3 bf16, 4 f32
    if (orA) mode = orB ? 3 : 4;
    else if (orC) mode = 0;
    else mode = orD ? 1 : 2;
    for (int i = tid; i < 1200; i += 256) deo[i] = ldin(de, i, bf);
    if (tid < 24) abo[tid] = ldin(ab, tid, bf);
    for (int wI = tid; wI < n / 32; wI += 256) {
        unsigned word = 0;
        for (int j = 0; j < 32; ++j) {
            int i = wI * 32 + j;
            int v;
            switch (mode) {
                case 0: v = p[i]; break;
                case 1: v = ((const int*)p)[i]; break;
                case 2: v = (int)((const long long*)p)[i]; break;
                case 3: v = ((const u16*)p)[i] != 0; break;
                default: v = (((const float*)p)[i] != 0.0f); break;
            }
            if (v) word |= 1u << j;
        }
        mbits[wI] = word;
    }
}

// ---------- bins ----------
__global__ void bins_kernel(const void* dist, unsigned char* bins,
                            const int* flagp, int n) {
    int bf = *flagp;
    int i = blockIdx.x * 256 + threadIdx.x;
    if (i < n) {
        float d = ldin(dist, i, bf);
        int v = (int)(d * 10.0f);
        v = v < 0 ? 0 : (v > 49 ? 49 : v);
        bins[i] = (unsigned char)v;
    }
}

// ---------- h init ----------
__global__ void init_h_kernel(const void* x, float* h, const int* flagp, int n) {
    int i = blockIdx.x * 256 + threadIdx.x;
    if (i < n) h[i] = ldin(x, i, *flagp);
}

// ---------- weight transpose: W[K][N] -> WT[N][K] bf16 ----------
__global__ __launch_bounds__(256) void wtrans_kernel(
    const void* Wqr, const void* Wkr, const void* Wvr, const void* Wor,
    const void* Wf1r, const void* Wf2r,
    u16* qkvT, u16* oT, u16* f1T, u16* f2T, const int* flagp) {
    int bf = *flagp;
    int bid = blockIdx.x;
    int l = bid >> 8, r = bid & 255;
    const void* src; u16* dst; long soff, doff; int Kd, Nd, t;
    if (r < 64) {
        int mat = r >> 4; t = r & 15; Kd = 128; Nd = 128;
        soff = (long)l * 16384;
        if (mat == 0)      { src = Wqr; dst = qkvT; doff = (long)l * 49152; }
        else if (mat == 1) { src = Wkr; dst = qkvT; doff = (long)l * 49152 + 16384; }
        else if (mat == 2) { src = Wvr; dst = qkvT; doff = (long)l * 49152 + 32768; }
        else               { src = Wor; dst = oT;   doff = (long)l * 16384; }
    } else if (r < 192) {
        t = r - 64; Kd = 128; Nd = 1024;
        src = Wf1r; soff = (long)l * 131072; dst = f1T; doff = (long)l * 131072;
    } else {
        t = r - 192; Kd = 512; Nd = 128;
        src = Wf2r; soff = (long)l * 65536; dst = f2T; doff = (long)l * 65536;
    }
    int ntile = Nd >> 5;
    int tk = t / ntile, tn = t % ntile;
    __shared__ u16 Ts[32][33];
    int rr = threadIdx.x >> 3, cc0 = (threadIdx.x & 7) * 4;
#pragma unroll
    for (int i = 0; i < 4; ++i) {
        long idx = soff + (long)(tk * 32 + rr) * Nd + tn * 32 + cc0 + i;
        Ts[rr][cc0 + i] = f2bf(ldin(src, idx, bf));
    }
    __syncthreads();
#pragma unroll
    for (int i = 0; i < 4; ++i) {
        long idx = doff + (long)(tn * 32 + rr) * Kd + tk * 32 + cc0 + i;
        dst[idx] = Ts[cc0 + i][rr];
    }
}

// ---------- LayerNorm: one wave per row; bf16 output ----------
__global__ __launch_bounds__(256) void ln_kernel(
    const float* __restrict__ h, const void* graw, const void* braw, long off,
    u16* __restrict__ out, const int* flagp) {
    int bf = *flagp;
    int row = blockIdx.x * 4 + (threadIdx.x >> 6);
    int lane = threadIdx.x & 63;
    const float* p = h + (size_t)row * Hq;
    float x0 = p[lane], x1 = p[lane + 64];
    float s = x0 + x1, s2 = x0 * x0 + x1 * x1;
#pragma unroll
    for (int o = 32; o; o >>= 1) {
        s += __shfl_xor(s, o);
        s2 += __shfl_xor(s2, o);
    }
    float mu = s * (1.0f / 128.0f);
    float var = fmaxf(s2 * (1.0f / 128.0f) - mu * mu, 0.0f);
    float rr = rsqrtf(var + 1e-5f);
    float g0 = ldin(graw, off + lane, bf), g1v = ldin(graw, off + lane + 64, bf);
    float b0 = ldin(braw, off + lane, bf), b1v = ldin(braw, off + lane + 64, bf);
    out[(size_t)row * Hq + lane]      = f2bf((x0 - mu) * rr * g0 + b0);
    out[(size_t)row * Hq + lane + 64] = f2bf((x1 - mu) * rr * g1v + b1v);
}

// ===== MFMA GEMM 64-row tile: A bf16 [M][K] @ WT bf16 [128][K] -> f32 (+resid) =====
// grid = M/64 = 256 blocks (full CU coverage). Optional bf16/f32 copy of result
// to outp (used to fold the final output conversion into the last FF2).
__global__ __launch_bounds__(256, 2) void mfma_gemm64_kernel(
    const u16* __restrict__ A, const u16* __restrict__ WT,
    const void* __restrict__ braw, long bOff, float* __restrict__ C,
    int K, int resid, const int* flagp, void* outp) {
    __shared__ __align__(16) u16 As[64][40];
    __shared__ __align__(16) u16 Bs[128][40];
    int tid = threadIdx.x;
    int m0 = blockIdx.x * 64;
    int wave = tid >> 6, lane = tid & 63;
    int wm = (wave >> 1) * 32, wn = (wave & 1) * 64;
    int q = lane >> 4, ln = lane & 15;
    f32x4 zero = {0.f, 0.f, 0.f, 0.f};
    f32x4 acc[2][4];
#pragma unroll
    for (int i = 0; i < 2; ++i)
#pragma unroll
        for (int j = 0; j < 4; ++j) acc[i][j] = zero;
    int sar = tid >> 2, sac = (tid & 3) * 8;
    int sbr = tid >> 1, sbc = (tid & 1) * 16;
    const u16* Ap = A + (size_t)(m0 + sar) * K + sac;
    const u16* Bp = WT + (size_t)sbr * K + sbc;
    for (int k0 = 0; k0 < K; k0 += 32) {
        uint4 av = *(const uint4*)(Ap + k0);
        uint4 b0 = *(const uint4*)(Bp + k0);
        uint4 b1 = *(const uint4*)(Bp + k0 + 8);
        *(uint4*)&As[sar][sac] = av;
        *(uint4*)&Bs[sbr][sbc] = b0; *(uint4*)&Bs[sbr][sbc + 8] = b1;
        __syncthreads();
        short8 af[2], bfv[4];
#pragma unroll
        for (int t = 0; t < 2; ++t) af[t] = *(const short8*)&As[wm + t * 16 + ln][q * 8];
#pragma unroll
        for (int t = 0; t < 4; ++t) bfv[t] = *(const short8*)&Bs[wn + t * 16 + ln][q * 8];
#pragma unroll
        for (int ti = 0; ti < 2; ++ti)
#pragma unroll
            for (int tj = 0; tj < 4; ++tj)
                acc[ti][tj] = __builtin_amdgcn_mfma_f32_16x16x32_bf16(
                    af[ti], bfv[tj], acc[ti][tj], 0, 0, 0);
        __syncthreads();
    }
    int bf = *flagp;
#pragma unroll
    for (int tj = 0; tj < 4; ++tj) {
        int n = wn + tj * 16 + ln;
        float bias = ldin(braw, bOff + n, bf);
#pragma unroll
        for (int ti = 0; ti < 2; ++ti)
#pragma unroll
            for (int r = 0; r < 4; ++r) {
                int m = m0 + wm + ti * 16 + q * 4 + r;
                float v = acc[ti][tj][r] + bias;
                float* dst = C + (size_t)m * 128 + n;
                if (resid) v += *dst;
                *dst = v;
                if (outp) {
                    if (bf) ((u16*)outp)[(size_t)m * 128 + n] = f2bf(v);
                    else ((float*)outp)[(size_t)m * 128 + n] = v;
                }
            }
    }
}

// QKV fused, 64-row tiles: grid (256, 3); outputs f16 bits; Q pre-scaled by 0.25
__global__ __launch_bounds__(256, 2) void qkv_mfma_kernel(
    const u16* __restrict__ A, const u16* __restrict__ qkvT_l,
    const void* bqr, const void* bkr, const void* bvr, long bOff,
    u16* __restrict__ Qo, u16* __restrict__ Ko, u16* __restrict__ Vo,
    const int* flagp) {
    int sel = blockIdx.y;
    const u16* WT = qkvT_l + (size_t)sel * 16384;
    const void* braw = sel == 0 ? bqr : (sel == 1 ? bkr : bvr);
    u16* C = sel == 0 ? Qo : (sel == 1 ? Ko : Vo);
    float scale = sel == 0 ? 0.25f : 1.0f;
    __shared__ __align__(16) u16 As[64][40];
    __shared__ __align__(16) u16 Bs[128][40];
    int tid = threadIdx.x;
    int m0 = blockIdx.x * 64;
    int wave = tid >> 6, lane = tid & 63;
    int wm = (wave >> 1) * 32, wn = (wave & 1) * 64;
    int q = lane >> 4, ln = lane & 15;
    f32x4 zero = {0.f, 0.f, 0.f, 0.f};
    f32x4 acc[2][4];
#pragma unroll
    for (int i = 0; i < 2; ++i)
#pragma unroll
        for (int j = 0; j < 4; ++j) acc[i][j] = zero;
    int sar = tid >> 2, sac = (tid & 3) * 8;
    int sbr = tid >> 1, sbc = (tid & 1) * 16;
    const u16* Ap = A + (size_t)(m0 + sar) * 128 + sac;
    const u16* Bp = WT + (size_t)sbr * 128 + sbc;
#pragma unroll
    for (int k0 = 0; k0 < 128; k0 += 32) {
        uint4 av = *(const uint4*)(Ap + k0);
        uint4 b0 = *(const uint4*)(Bp + k0);
        uint4 b1 = *(const uint4*)(Bp + k0 + 8);
        *(uint4*)&As[sar][sac] = av;
        *(uint4*)&Bs[sbr][sbc] = b0; *(uint4*)&Bs[sbr][sbc + 8] = b1;
        __syncthreads();
        short8 af[2], bfv[4];
#pragma unroll
        for (int t = 0; t < 2; ++t) af[t] = *(const short8*)&As[wm + t * 16 + ln][q * 8];
#pragma unroll
        for (int t = 0; t < 4; ++t) bfv[t] = *(const short8*)&Bs[wn + t * 16 + ln][q * 8];
#pragma unroll
        for (int ti = 0; ti < 2; ++ti)
#pragma unroll
            for (int tj = 0; tj < 4; ++tj)
                acc[ti][tj] = __builtin_amdgcn_mfma_f32_16x16x32_bf16(
                    af[ti], bfv[tj], acc[ti][tj], 0, 0, 0);
        __syncthreads();
    }
    int bf = *flagp;
#pragma unroll
    for (int tj = 0; tj < 4; ++tj) {
        int n = wn + tj * 16 + ln;
        float bias = ldin(braw, bOff + n, bf);
#pragma unroll
        for (int ti = 0; ti < 2; ++ti)
#pragma unroll
            for (int r = 0; r < 4; ++r) {
                int m = m0 + wm + ti * 16 + q * 4 + r;
                C[(size_t)m * 128 + n] = f2h((acc[ti][tj][r] + bias) * scale);
            }
    }
}

// GLU-FF1 (unchanged; grid (128,8) = 1024 blocks already saturates)
__global__ __launch_bounds__(256, 2) void glu_mfma_kernel(
    const u16* __restrict__ A, const u16* __restrict__ f1T_l,
    const void* __restrict__ braw, long bOff, u16* __restrict__ Vout,
    const int* flagp) {
    __shared__ __align__(16) u16 As[128][40];
    __shared__ __align__(16) u16 Ba[64][40];
    __shared__ __align__(16) u16 Bb[64][40];
    int tid = threadIdx.x;
    int m0 = blockIdx.x * 128, n0 = blockIdx.y * 64;
    int wave = tid >> 6, lane = tid & 63;
    int wm = (wave >> 1) * 64, wn = (wave & 1) * 32;
    int q = lane >> 4, ln = lane & 15;
    f32x4 zero = {0.f, 0.f, 0.f, 0.f};
    f32x4 accA[4][2], accB[4][2];
#pragma unroll
    for (int i = 0; i < 4; ++i)
#pragma unroll
        for (int j = 0; j < 2; ++j) { accA[i][j] = zero; accB[i][j] = zero; }
    int sr = tid >> 1, sc = (tid & 1) * 16;
    const u16* Ap = A + (size_t)(m0 + sr) * 128 + sc;
    const u16* BpA = f1T_l + (size_t)(n0 + sr) * 128 + sc;
    const u16* BpB = f1T_l + (size_t)(512 + n0 + (sr - 64)) * 128 + sc;
#pragma unroll
    for (int k0 = 0; k0 < 128; k0 += 32) {
        uint4 a0 = *(const uint4*)(Ap + k0);
        uint4 a1 = *(const uint4*)(Ap + k0 + 8);
        *(uint4*)&As[sr][sc] = a0; *(uint4*)&As[sr][sc + 8] = a1;
        if (sr < 64) {
            uint4 w0 = *(const uint4*)(BpA + k0);
            uint4 w1 = *(const uint4*)(BpA + k0 + 8);
            *(uint4*)&Ba[sr][sc] = w0; *(uint4*)&Ba[sr][sc + 8] = w1;
        } else {
            uint4 w0 = *(const uint4*)(BpB + k0);
            uint4 w1 = *(const uint4*)(BpB + k0 + 8);
            *(uint4*)&Bb[sr - 64][sc] = w0; *(uint4*)&Bb[sr - 64][sc + 8] = w1;
        }
        __syncthreads();
        short8 af[4], ba[2], bb[2];
#pragma unroll
        for (int t = 0; t < 4; ++t) af[t] = *(const short8*)&As[wm + t * 16 + ln][q * 8];
#pragma unroll
        for (int t = 0; t < 2; ++t) {
            ba[t] = *(const short8*)&Ba[wn + t * 16 + ln][q * 8];
            bb[t] = *(const short8*)&Bb[wn + t * 16 + ln][q * 8];
        }
#pragma unroll
        for (int ti = 0; ti < 4; ++ti)
#pragma unroll
            for (int tj = 0; tj < 2; ++tj) {
                accA[ti][tj] = __builtin_amdgcn_mfma_f32_16x16x32_bf16(
                    af[ti], ba[tj], accA[ti][tj], 0, 0, 0);
                accB[ti][tj] = __builtin_amdgcn_mfma_f32_16x16x32_bf16(
                    af[ti], bb[tj], accB[ti][tj], 0, 0, 0);
            }
        __syncthreads();
    }
    int bf = *flagp;
#pragma unroll
    for (int tj = 0; tj < 2; ++tj) {
        int n = n0 + wn + tj * 16 + ln;
        float biasA = ldin(braw, bOff + n, bf);
        float biasB = ldin(braw, bOff + 512 + n, bf);
#pragma unroll
        for (int ti = 0; ti < 4; ++ti)
#pragma unroll
            for (int r = 0; r < 4; ++r) {
                int m = m0 + wm + ti * 16 + q * 4 + r;
                float ua = accA[ti][tj][r] + biasA;
                float ub = accB[ti][tj][r] + biasB;
                Vout[(size_t)m * 512 + n] = f2bf(ua / (1.0f + __expf(-ub)));
            }
    }
}

// ================== attention v4: full-MFMA, 4 blocks/CU, bins prefetch =========
// LDS 38.3 KB: KsF frag-major 16 KB (conflict-free aligned b128) + VT 16.25 KB
// + Pl 5 KB. S^T = K Q^T; P f16 via wave-private LDS; O = P V; fixed-shift
// softmax; masked -> p = 0; bins dwords prefetched one kt ahead.
__global__ __launch_bounds__(256, 4) void attn_kernel(
    const u16* __restrict__ Qh, const u16* __restrict__ Kh,
    const u16* __restrict__ Vh, const unsigned char* __restrict__ bins,
    const unsigned int* __restrict__ mbits, const float* __restrict__ deL,
    const float* __restrict__ abL, u16* __restrict__ out) {
    // de-swizzle: heads of one (b,qq) share id%8 -> same XCD L2 for bins
    int id = blockIdx.x;
    int c = id & 7, t5 = id >> 3;
    int nh = t5 & 7;
    int pair = ((t5 >> 3) << 3) | c;
    int b = pair >> 2, qq = pair & 3;

    __shared__ __align__(16) u16 KsF[8192];      // frag-major K, 16 KB
    __shared__ __align__(16) u16 VT[16 * 520];   // V^T rows 520 f16, 16.25 KB
    __shared__ __align__(16) u16 Pl[4 * 16 * 40];// per-wave P tile, 5 KB

    int tid = threadIdx.x;
    const u16* Kp = Kh + (size_t)(b * Nq) * Hq + nh * HDq;
    const u16* Vp = Vh + (size_t)(b * Nq) * Hq + nh * HDq;
    for (int r = tid; r < Nq; r += 256) {
        int kt = r >> 5, s = (r >> 4) & 1, lnr = r & 15;
        uint4 k0v = *(const uint4*)(Kp + (size_t)r * Hq);
        uint4 k1v = *(const uint4*)(Kp + (size_t)r * Hq + 8);
        *(uint4*)&KsF[kt * 512 + s * 256 + lnr * 8]       = k0v;  // d 0..7
        *(uint4*)&KsF[kt * 512 + s * 256 + 128 + lnr * 8] = k1v;  // d 8..15
        uint4 v0 = *(const uint4*)(Vp + (size_t)r * Hq);
        uint4 v1 = *(const uint4*)(Vp + (size_t)r * Hq + 8);
        u16 vv[16];
        *(uint4*)&vv[0] = v0; *(uint4*)&vv[8] = v1;
#pragma unroll
        for (int d = 0; d < 16; ++d) VT[d * 520 + r] = vv[d];
    }
    __syncthreads();

    int wave = tid >> 6, lane = tid & 63;
    int quad = lane >> 4, ln = lane & 15;
    int q0w = qq * 128 + wave * 32;

    float tbl = (lane < 50) ? deL[lane * NHq + nh] + abL[nh] : 0.0f;
    unsigned mwall = (lane < 16) ? mbits[b * 16 + lane] : 0u;

    // hoisted Q B-frags (quads 2,3 supply the zero d-padding)
    half8 qf[2];
#pragma unroll
    for (int t = 0; t < 2; ++t) {
        uint4 qv = {0, 0, 0, 0};
        if (quad < 2)
            qv = *(const uint4*)(Qh + (size_t)(b * Nq + q0w + t * 16 + ln) * Hq
                                 + nh * HDq + quad * 8);
        qf[t] = *(half8*)&qv;
    }

    f32x4 zero = {0.f, 0.f, 0.f, 0.f};
    f32x4 acc[2] = {zero, zero};
    float zp[2] = {0.f, 0.f};
    _Float16* Pw = (_Float16*)&Pl[wave * 640];
    const _Float16* KsH = (const _Float16*)KsF;
    const _Float16* VTH = (const _Float16*)VT;
    const unsigned char* brow0 = bins + (size_t)b * Nq * Nq + (size_t)(q0w + ln) * Nq;
    const unsigned char* brow1 = brow0 + (size_t)16 * Nq;

    // prefetch kt=0 bins dwords
    unsigned pb00 = *(const unsigned*)(brow0 + quad * 4);
    unsigned pb01 = *(const unsigned*)(brow0 + 16 + quad * 4);
    unsigned pb10 = *(const unsigned*)(brow1 + quad * 4);
    unsigned pb11 = *(const unsigned*)(brow1 + 16 + quad * 4);

    for (int kt = 0; kt < 16; ++kt) {
        int k0 = kt * 32;
        unsigned w = (unsigned)__shfl((int)mwall, kt);
        unsigned cb00 = pb00, cb01 = pb01, cb10 = pb10, cb11 = pb11;
        if (kt < 15) {
            pb00 = *(const unsigned*)(brow0 + k0 + 32 + quad * 4);
            pb01 = *(const unsigned*)(brow0 + k0 + 48 + quad * 4);
            pb10 = *(const unsigned*)(brow1 + k0 + 32 + quad * 4);
            pb11 = *(const unsigned*)(brow1 + k0 + 48 + quad * 4);
        }
        half8 vb = *(const half8*)(VTH + ln * 520 + k0 + quad * 8);
        half8 ka0 = {}, ka1 = {};
        if (quad < 2) {
            ka0 = *(const half8*)(KsH + kt * 512 + quad * 128 + ln * 8);
            ka1 = *(const half8*)(KsH + kt * 512 + 256 + quad * 128 + ln * 8);
        }
#pragma unroll
        for (int t = 0; t < 2; ++t) {
            unsigned bw0 = t == 0 ? cb00 : cb10;
            unsigned bw1 = t == 0 ? cb01 : cb11;
            f32x4 s0 = __builtin_amdgcn_mfma_f32_16x16x32_f16(ka0, qf[t], zero, 0, 0, 0);
            f32x4 s1 = __builtin_amdgcn_mfma_f32_16x16x32_f16(ka1, qf[t], zero, 0, 0, 0);
            float p[8];
#pragma unroll
            for (int r = 0; r < 4; ++r) {
                float sc = s0[r] + __shfl(tbl, (int)((bw0 >> (8 * r)) & 0xFFu));
                bool m = (w >> (quad * 4 + r)) & 1u;
                p[r] = m ? 0.0f : __expf(sc);
            }
#pragma unroll
            for (int r = 0; r < 4; ++r) {
                float sc = s1[r] + __shfl(tbl, (int)((bw1 >> (8 * r)) & 0xFFu));
                bool m = (w >> (16 + quad * 4 + r)) & 1u;
                p[4 + r] = m ? 0.0f : __expf(sc);
            }
            zp[t] += ((p[0] + p[1]) + (p[2] + p[3])) +
                     ((p[4] + p[5]) + (p[6] + p[7]));
            uint2 w0, w1;
            w0.x = pk2h(p[0], p[1]); w0.y = pk2h(p[2], p[3]);
            w1.x = pk2h(p[4], p[5]); w1.y = pk2h(p[6], p[7]);
            *(uint2*)(Pw + ln * 40 + quad * 4)      = w0;   // k = quad*4+r
            *(uint2*)(Pw + ln * 40 + 16 + quad * 4) = w1;   // k = 16+quad*4+r
            half8 pa = *(const half8*)(Pw + ln * 40 + quad * 8); // A[m=ln][k=quad*8+j]
            acc[t] = __builtin_amdgcn_mfma_f32_16x16x32_f16(pa, vb, acc[t], 0, 0, 0);
        }
    }
#pragma unroll
    for (int t = 0; t < 2; ++t) {
        zp[t] += __shfl_xor(zp[t], 16);
        zp[t] += __shfl_xor(zp[t], 32);
    }
#pragma unroll
    for (int t = 0; t < 2; ++t) {
#pragma unroll
        for (int r = 0; r < 4; ++r) {
            float zz = __shfl(zp[t], quad * 4 + r);
            float val = acc[t][r] / fmaxf(zz, 1e-35f);
            int qrow = q0w + t * 16 + quad * 4 + r;
            out[(size_t)(b * Nq + qrow) * Hq + nh * HDq + ln] = f2bf(val);
        }
    }
}

extern "C" void kernel_launch(void* const* d_in, const int* in_sizes, int n_in,
                              void* d_out, int out_size, void* d_ws, size_t ws_size,
                              hipStream_t stream) {
    const void* x  = d_in[0];
    const void* dist = d_in[1];
    const void* mask = d_in[2];
    const void* Wq = d_in[3];  const void* bq = d_in[4];
    const void* Wk = d_in[5];  const void* bk = d_in[6];
    const void* Wv = d_in[7];  const void* bv = d_in[8];
    const void* Wo = d_in[9];  const void* bo = d_in[10];
    const void* de = d_in[11]; const void* ab = d_in[12];
    const void* g1 = d_in[13]; const void* b1 = d_in[14];
    const void* g2 = d_in[15]; const void* b2 = d_in[16];
    const void* Wf1 = d_in[17]; const void* bf1 = d_in[18];
    const void* Wf2 = d_in[19]; const void* bf2 = d_in[20];

    char* ws = (char*)d_ws;
    const size_t OFF_DE   = 64;
    const size_t OFF_AB   = 5120;
    const size_t OFF_BINS = 8192;                    // 8,388,608
    const size_t OFF_MSK  = OFF_BINS + 8388608;      // 4096
    const size_t OFF_H    = OFF_MSK + 4096;          // f32 8,388,608
    const size_t OFF_QKV  = OFF_H + 8388608;         // Qh,Kh,Vh f16 (3x4MB) | vglu u16 16MB
    const size_t OFF_HN   = OFF_QKV + 25165824;      // u16 4,194,304
    const size_t OFF_ATT  = OFF_HN + 4194304;        // u16 4,194,304
    const size_t OFF_WT   = OFF_ATT + 4194304;       // u16 1,572,864
    const size_t NEEDED   = OFF_WT + 1572864;
    if (ws_size < NEEDED) return;

    int* flag = (int*)ws;
    float* deF = (float*)(ws + OFF_DE);
    float* abF = (float*)(ws + OFF_AB);
    unsigned char* bins = (unsigned char*)(ws + OFF_BINS);
    unsigned* mbits = (unsigned*)(ws + OFF_MSK);
    float* h = (float*)(ws + OFF_H);
    u16* Qh = (u16*)(ws + OFF_QKV);
    u16* Kh = Qh + 2097152;
    u16* Vh = Qh + 2 * 2097152;
    u16* vglu = (u16*)(ws + OFF_QKV);
    u16* hn = (u16*)(ws + OFF_HN);
    u16* att = (u16*)(ws + OFF_ATT);
    u16* qkvT = (u16*)(ws + OFF_WT);
    u16* oT  = qkvT + 147456;
    u16* f1T = oT + 49152;
    u16* f2T = f1T + 393216;

    prep_kernel<<<1, 256, 0, stream>>>(x, de, ab, mask, flag, deF, abF, mbits, Bq * Nq);
    bins_kernel<<<32768, 256, 0, stream>>>(dist, bins, flag, Bq * Nq * Nq);
    init_h_kernel<<<8192, 256, 0, stream>>>(x, h, flag, Mq * Hq);
    wtrans_kernel<<<768, 256, 0, stream>>>(Wq, Wk, Wv, Wo, Wf1, Wf2,
                                           qkvT, oT, f1T, f2T, flag);

    dim3 gqkv(256, 3);
    dim3 gglu(128, 8);
    for (int l = 0; l < 3; ++l) {
        ln_kernel<<<4096, 256, 0, stream>>>(h, g1, b1, (long)l * Hq, hn, flag);
        qkv_mfma_kernel<<<gqkv, 256, 0, stream>>>(hn, qkvT + (size_t)l * 49152,
                                                  bq, bk, bv, (long)l * Hq,
                                                  Qh, Kh, Vh, flag);
        attn_kernel<<<1024, 256, 0, stream>>>(Qh, Kh, Vh, bins, mbits,
                                              deF + (long)l * 400, abF + (long)l * 8, att);
        mfma_gemm64_kernel<<<256, 256, 0, stream>>>(att, oT + (size_t)l * 16384,
                                                    bo, (long)l * Hq, h, 128, 1, flag,
                                                    nullptr);
        ln_kernel<<<4096, 256, 0, stream>>>(h, g2, b2, (long)l * Hq, hn, flag);
        glu_mfma_kernel<<<gglu, 256, 0, stream>>>(hn, f1T + (size_t)l * 131072,
                                                  bf1, (long)l * 1024, vglu, flag);
        mfma_gemm64_kernel<<<256, 256, 0, stream>>>(vglu, f2T + (size_t)l * 65536,
                                                    bf2, (long)l * Hq, h, 512, 1, flag,
                                                    (l == 2) ? d_out : nullptr);
    }
}

// Round 7
// 409.631 us; speedup vs baseline: 5.8623x; 1.1456x over previous
//
#include <hip/hip_runtime.h>
#include <stdint.h>

#define Bq 32
#define Nq 512
#define Hq 128
#define NHq 8
#define HDq 16
#define Mq (Bq * Nq)   // 16384

typedef unsigned short u16;
typedef __attribute__((ext_vector_type(8))) short short8;
typedef __attribute__((ext_vector_type(8))) _Float16 half8;
typedef __attribute__((ext_vector_type(2))) __fp16 fp16x2;
typedef __attribute__((ext_vector_type(4))) float f32x4;

// ---------- dtype-flex helpers (flag: 1 = inputs are bf16, 0 = f32) ----------
__device__ __forceinline__ float bf2f(u16 v) {
    return __uint_as_float(((unsigned int)v) << 16);
}
__device__ __forceinline__ float ldin(const void* p, long idx, int bf) {
    if (bf) return bf2f(((const u16*)p)[idx]);
    return ((const float*)p)[idx];
}
__device__ __forceinline__ u16 f2bf(float v) {   // RNE
    unsigned int u = __float_as_uint(v);
    return (u16)((u + 0x7FFFu + ((u >> 16) & 1u)) >> 16);
}
__device__ __forceinline__ u16 f2h(float v) {    // f32 -> f16 bits (RNE)
    _Float16 h = (_Float16)v;
    return *(u16*)&h;
}
__device__ __forceinline__ unsigned pk2h(float a, float b) {  // packed f16 pair bits
    fp16x2 c = __builtin_amdgcn_cvt_pkrtz(a, b);
    return *(unsigned*)&c;
}

// ---------- merged prep: dtype detect + small converts + mask bit-words ----------
__global__ void prep_kernel(const void* xraw, const void* de, const void* ab,
                            const void* mraw, int* flag, float* deo, float* abo,
                            unsigned* mbits, int n) {
    __shared__ int cnt, orA, orB, orC, orD;
    int tid = threadIdx.x;
    if (tid == 0) { cnt = 0; orA = 0; orB = 0; orC = 0; orD = 0; }
    __syncthreads();
    const u16* u = (const u16*)xraw;
    int good = 0;
    for (int i = tid; i < 1024; i += 256) {
        u16 v = u[i];
        int e = (v >> 7) & 0xFF;
        if (v == 0 || (e >= 90 && e <= 141)) good++;
    }
    atomicAdd(&cnt, good);
    // vectorized mask encoding scan over first n bytes
    const uint4* p4 = (const uint4*)mraw;
    unsigned a = 0, b = 0, c = 0, d = 0;
    for (int i = tid; i < n / 16; i += 256) {
        uint4 w = p4[i];
        unsigned all = w.x | w.y | w.z | w.w;
        a |= all & 0xFEFEFEFEu;
        b |= all & 0x0000FF00u;
        c |= all & 0xFFFFFF00u;
        d |= w.y | w.w;
    }
    if (a) atomicOr(&orA, 1);
    if (b) atomicOr(&orB, 1);
    if (c) atomicOr(&orC, 1);
    if (d) atomicOr(&orD, 1);
    __syncthreads();
    int bf = (cnt >= 900);
    if (tid == 0) *flag = bf;
    int mode;  // 0 bool8, 1 int32, 2 int64, 3 bf16, 4 f32
    if (orA) mode = orB ? 3 : 4;
    else if (orC) mode = 0;
    else mode = orD ? 1 : 2;
    for (int i = tid; i < 1200; i += 256) deo[i] = ldin(de, i, bf);
    if (tid < 24) abo[tid] = ldin(ab, tid, bf);
    const unsigned char* p = (const unsigned char*)mraw;
    for (int wI = tid; wI < n / 32; wI += 256) {
        unsigned word = 0;
        for (int j = 0; j < 32; ++j) {
            int i = wI * 32 + j;
            int v;
            switch (mode) {
                case 0: v = p[i]; break;
                case 1: v = ((const int*)p)[i]; break;
                case 2: v = (int)((const long long*)p)[i]; break;
                case 3: v = ((const u16*)p)[i] != 0; break;
                default: v = (((const float*)p)[i] != 0.0f); break;
            }
            if (v) word |= 1u << j;
        }
        mbits[wI] = word;
    }
}

// ---------- kprep: per-batch compressed unmasked-k index list ----------
// kidxg[b][j] (u16), nkt[b] = #32-tiles, tmask[b][t] bit=1 -> padded/masked slot
__global__ void kprep_kernel(const unsigned* __restrict__ mbits,
                             u16* __restrict__ kidxg, int* __restrict__ nkt,
                             unsigned* __restrict__ tmask) {
    int b = blockIdx.x;
    int lane = threadIdx.x & 63;
    int pos_base = 0;
    for (int w = 0; w < 8; ++w) {
        unsigned lo = mbits[b * 16 + 2 * w], hi = mbits[b * 16 + 2 * w + 1];
        unsigned long long word = ((unsigned long long)hi << 32) | lo;
        unsigned long long un = ~word;   // 1 = unmasked
        int bit = (int)((un >> lane) & 1ull);
        unsigned long long before = un & ((1ull << lane) - 1ull);
        int pos = pos_base + __popcll(before);
        if (bit) kidxg[b * 512 + pos] = (u16)(w * 64 + lane);
        pos_base += __popcll(un);
    }
    int nk = pos_base;
    int nkp = (nk + 31) & ~31;
    if (nkp == 0) nkp = 32;
    int nt = nkp >> 5;
    for (int j = nk + lane; j < nkp; j += 64) kidxg[b * 512 + j] = 0;
    if (lane == 0) {
        nkt[b] = nt;
        for (int t = 0; t < 16; ++t) tmask[b * 16 + t] = 0;
        int rem = nk & 31;
        if (rem) tmask[b * 16 + nt - 1] = 0xFFFFFFFFu << rem;
        if (nk == 0) tmask[b * 16] = 0xFFFFFFFFu;
    }
}

// ---------- binsc: compressed, pre-scaled (x4) bin bytes from dist ----------
__global__ __launch_bounds__(256) void binsc_kernel(
    const void* __restrict__ dist, const u16* __restrict__ kidxg,
    const int* __restrict__ nkt, unsigned char* __restrict__ binsc,
    const int* flagp) {
    int bf = *flagp;
    int b = blockIdx.y;
    int q0 = blockIdx.x * 8;
    __shared__ u16 kl[512];
    __shared__ int ntS;
    int tid = threadIdx.x;
    if (tid == 0) ntS = nkt[b];
    kl[tid] = kidxg[b * 512 + tid];
    kl[tid + 256] = kidxg[b * 512 + tid + 256];
    __syncthreads();
    int nkp = ntS * 32;
    for (int rq = 0; rq < 8; ++rq) {
        int q = q0 + rq;
        long rowoff = ((long)b * 512 + q) * 512;
        for (int j = tid; j < nkp; j += 256) {
            float d = ldin(dist, rowoff + kl[j], bf);
            int v = (int)(d * 10.0f);
            v = v < 0 ? 0 : (v > 49 ? 49 : v);
            binsc[((size_t)b * 512 + q) * 512 + j] = (unsigned char)(v << 2);
        }
    }
}

// ---------- init + first LN: x -> h (f32) and hn = LN(x) (bf16) ----------
__global__ __launch_bounds__(256) void init_ln_kernel(
    const void* x, float* __restrict__ h, u16* __restrict__ hn,
    const void* graw, const void* braw, const int* flagp) {
    int bf = *flagp;
    int row = blockIdx.x * 4 + (threadIdx.x >> 6);
    int lane = threadIdx.x & 63;
    float x0 = ldin(x, (long)row * Hq + lane, bf);
    float x1 = ldin(x, (long)row * Hq + lane + 64, bf);
    h[(size_t)row * Hq + lane] = x0;
    h[(size_t)row * Hq + lane + 64] = x1;
    float s = x0 + x1, s2 = x0 * x0 + x1 * x1;
#pragma unroll
    for (int o = 32; o; o >>= 1) {
        s += __shfl_xor(s, o);
        s2 += __shfl_xor(s2, o);
    }
    float mu = s * (1.0f / 128.0f);
    float var = fmaxf(s2 * (1.0f / 128.0f) - mu * mu, 0.0f);
    float rr = rsqrtf(var + 1e-5f);
    float g0 = ldin(graw, lane, bf), g1v = ldin(graw, lane + 64, bf);
    float b0 = ldin(braw, lane, bf), b1v = ldin(braw, lane + 64, bf);
    hn[(size_t)row * Hq + lane]      = f2bf((x0 - mu) * rr * g0 + b0);
    hn[(size_t)row * Hq + lane + 64] = f2bf((x1 - mu) * rr * g1v + b1v);
}

// ---------- weight transpose: W[K][N] -> WT[N][K] bf16 ----------
__global__ __launch_bounds__(256) void wtrans_kernel(
    const void* Wqr, const void* Wkr, const void* Wvr, const void* Wor,
    const void* Wf1r, const void* Wf2r,
    u16* qkvT, u16* oT, u16* f1T, u16* f2T, const int* flagp) {
    int bf = *flagp;
    int bid = blockIdx.x;
    int l = bid >> 8, r = bid & 255;
    const void* src; u16* dst; long soff, doff; int Kd, Nd, t;
    if (r < 64) {
        int mat = r >> 4; t = r & 15; Kd = 128; Nd = 128;
        soff = (long)l * 16384;
        if (mat == 0)      { src = Wqr; dst = qkvT; doff = (long)l * 49152; }
        else if (mat == 1) { src = Wkr; dst = qkvT; doff = (long)l * 49152 + 16384; }
        else if (mat == 2) { src = Wvr; dst = qkvT; doff = (long)l * 49152 + 32768; }
        else               { src = Wor; dst = oT;   doff = (long)l * 16384; }
    } else if (r < 192) {
        t = r - 64; Kd = 128; Nd = 1024;
        src = Wf1r; soff = (long)l * 131072; dst = f1T; doff = (long)l * 131072;
    } else {
        t = r - 192; Kd = 512; Nd = 128;
        src = Wf2r; soff = (long)l * 65536; dst = f2T; doff = (long)l * 65536;
    }
    int ntile = Nd >> 5;
    int tk = t / ntile, tn = t % ntile;
    __shared__ u16 Ts[32][33];
    int rr = threadIdx.x >> 3, cc0 = (threadIdx.x & 7) * 4;
#pragma unroll
    for (int i = 0; i < 4; ++i) {
        long idx = soff + (long)(tk * 32 + rr) * Nd + tn * 32 + cc0 + i;
        Ts[rr][cc0 + i] = f2bf(ldin(src, idx, bf));
    }
    __syncthreads();
#pragma unroll
    for (int i = 0; i < 4; ++i) {
        long idx = doff + (long)(tn * 32 + rr) * Kd + tk * 32 + cc0 + i;
        dst[idx] = Ts[cc0 + i][rr];
    }
}

// ===== MFMA GEMM 64-row tile + optional fused LN and/or final-output copy ======
__global__ __launch_bounds__(256, 2) void mfma_gemm64_kernel(
    const u16* __restrict__ A, const u16* __restrict__ WT,
    const void* __restrict__ braw, long bOff, float* __restrict__ C,
    int K, int resid, const int* flagp,
    const void* lnG, const void* lnB, long lnOff, u16* hnout, void* outp) {
    __shared__ __align__(16) u16 As[64][40];
    __shared__ __align__(16) u16 Bs[128][40];
    __shared__ float Ct[64][128];
    int tid = threadIdx.x;
    int m0 = blockIdx.x * 64;
    int wave = tid >> 6, lane = tid & 63;
    int wm = (wave >> 1) * 32, wn = (wave & 1) * 64;
    int q = lane >> 4, ln = lane & 15;
    f32x4 zero = {0.f, 0.f, 0.f, 0.f};
    f32x4 acc[2][4];
#pragma unroll
    for (int i = 0; i < 2; ++i)
#pragma unroll
        for (int j = 0; j < 4; ++j) acc[i][j] = zero;
    int sar = tid >> 2, sac = (tid & 3) * 8;
    int sbr = tid >> 1, sbc = (tid & 1) * 16;
    const u16* Ap = A + (size_t)(m0 + sar) * K + sac;
    const u16* Bp = WT + (size_t)sbr * K + sbc;
    for (int k0 = 0; k0 < K; k0 += 32) {
        uint4 av = *(const uint4*)(Ap + k0);
        uint4 b0 = *(const uint4*)(Bp + k0);
        uint4 b1 = *(const uint4*)(Bp + k0 + 8);
        *(uint4*)&As[sar][sac] = av;
        *(uint4*)&Bs[sbr][sbc] = b0; *(uint4*)&Bs[sbr][sbc + 8] = b1;
        __syncthreads();
        short8 af[2], bfv[4];
#pragma unroll
        for (int t = 0; t < 2; ++t) af[t] = *(const short8*)&As[wm + t * 16 + ln][q * 8];
#pragma unroll
        for (int t = 0; t < 4; ++t) bfv[t] = *(const short8*)&Bs[wn + t * 16 + ln][q * 8];
#pragma unroll
        for (int ti = 0; ti < 2; ++ti)
#pragma unroll
            for (int tj = 0; tj < 4; ++tj)
                acc[ti][tj] = __builtin_amdgcn_mfma_f32_16x16x32_bf16(
                    af[ti], bfv[tj], acc[ti][tj], 0, 0, 0);
        __syncthreads();
    }
    int bf = *flagp;
#pragma unroll
    for (int tj = 0; tj < 4; ++tj) {
        int n = wn + tj * 16 + ln;
        float bias = ldin(braw, bOff + n, bf);
#pragma unroll
        for (int ti = 0; ti < 2; ++ti)
#pragma unroll
            for (int r = 0; r < 4; ++r) {
                int m = m0 + wm + ti * 16 + q * 4 + r;
                float v = acc[ti][tj][r] + bias;
                float* dst = C + (size_t)m * 128 + n;
                if (resid) v += *dst;
                *dst = v;
                Ct[m - m0][n] = v;
                if (outp) {
                    if (bf) ((u16*)outp)[(size_t)m * 128 + n] = f2bf(v);
                    else ((float*)outp)[(size_t)m * 128 + n] = v;
                }
            }
    }
    if (hnout) {
        __syncthreads();
        float gg0 = ldin(lnG, lnOff + lane, bf);
        float gg1 = ldin(lnG, lnOff + lane + 64, bf);
        float bb0 = ldin(lnB, lnOff + lane, bf);
        float bb1 = ldin(lnB, lnOff + lane + 64, bf);
        for (int rr = 0; rr < 16; ++rr) {
            int row = wave * 16 + rr;
            float x0 = Ct[row][lane], x1 = Ct[row][lane + 64];
            float s = x0 + x1, s2v = x0 * x0 + x1 * x1;
#pragma unroll
            for (int o = 32; o; o >>= 1) {
                s += __shfl_xor(s, o);
                s2v += __shfl_xor(s2v, o);
            }
            float mu = s * (1.0f / 128.0f);
            float var = fmaxf(s2v * (1.0f / 128.0f) - mu * mu, 0.0f);
            float rstd = rsqrtf(var + 1e-5f);
            int m = m0 + row;
            hnout[(size_t)m * 128 + lane]      = f2bf((x0 - mu) * rstd * gg0 + bb0);
            hnout[(size_t)m * 128 + lane + 64] = f2bf((x1 - mu) * rstd * gg1 + bb1);
        }
    }
}

// QKV fused, 64-row tiles: grid (256, 3); outputs f16 bits; Q pre-scaled by 0.25
__global__ __launch_bounds__(256, 2) void qkv_mfma_kernel(
    const u16* __restrict__ A, const u16* __restrict__ qkvT_l,
    const void* bqr, const void* bkr, const void* bvr, long bOff,
    u16* __restrict__ Qo, u16* __restrict__ Ko, u16* __restrict__ Vo,
    const int* flagp) {
    int sel = blockIdx.y;
    const u16* WT = qkvT_l + (size_t)sel * 16384;
    const void* braw = sel == 0 ? bqr : (sel == 1 ? bkr : bvr);
    u16* C = sel == 0 ? Qo : (sel == 1 ? Ko : Vo);
    float scale = sel == 0 ? 0.25f : 1.0f;
    __shared__ __align__(16) u16 As[64][40];
    __shared__ __align__(16) u16 Bs[128][40];
    int tid = threadIdx.x;
    int m0 = blockIdx.x * 64;
    int wave = tid >> 6, lane = tid & 63;
    int wm = (wave >> 1) * 32, wn = (wave & 1) * 64;
    int q = lane >> 4, ln = lane & 15;
    f32x4 zero = {0.f, 0.f, 0.f, 0.f};
    f32x4 acc[2][4];
#pragma unroll
    for (int i = 0; i < 2; ++i)
#pragma unroll
        for (int j = 0; j < 4; ++j) acc[i][j] = zero;
    int sar = tid >> 2, sac = (tid & 3) * 8;
    int sbr = tid >> 1, sbc = (tid & 1) * 16;
    const u16* Ap = A + (size_t)(m0 + sar) * 128 + sac;
    const u16* Bp = WT + (size_t)sbr * 128 + sbc;
#pragma unroll
    for (int k0 = 0; k0 < 128; k0 += 32) {
        uint4 av = *(const uint4*)(Ap + k0);
        uint4 b0 = *(const uint4*)(Bp + k0);
        uint4 b1 = *(const uint4*)(Bp + k0 + 8);
        *(uint4*)&As[sar][sac] = av;
        *(uint4*)&Bs[sbr][sbc] = b0; *(uint4*)&Bs[sbr][sbc + 8] = b1;
        __syncthreads();
        short8 af[2], bfv[4];
#pragma unroll
        for (int t = 0; t < 2; ++t) af[t] = *(const short8*)&As[wm + t * 16 + ln][q * 8];
#pragma unroll
        for (int t = 0; t < 4; ++t) bfv[t] = *(const short8*)&Bs[wn + t * 16 + ln][q * 8];
#pragma unroll
        for (int ti = 0; ti < 2; ++ti)
#pragma unroll
            for (int tj = 0; tj < 4; ++tj)
                acc[ti][tj] = __builtin_amdgcn_mfma_f32_16x16x32_bf16(
                    af[ti], bfv[tj], acc[ti][tj], 0, 0, 0);
        __syncthreads();
    }
    int bf = *flagp;
#pragma unroll
    for (int tj = 0; tj < 4; ++tj) {
        int n = wn + tj * 16 + ln;
        float bias = ldin(braw, bOff + n, bf);
#pragma unroll
        for (int ti = 0; ti < 2; ++ti)
#pragma unroll
            for (int r = 0; r < 4; ++r) {
                int m = m0 + wm + ti * 16 + q * 4 + r;
                C[(size_t)m * 128 + n] = f2h((acc[ti][tj][r] + bias) * scale);
            }
    }
}

// GLU-FF1 (unchanged)
__global__ __launch_bounds__(256, 2) void glu_mfma_kernel(
    const u16* __restrict__ A, const u16* __restrict__ f1T_l,
    const void* __restrict__ braw, long bOff, u16* __restrict__ Vout,
    const int* flagp) {
    __shared__ __align__(16) u16 As[128][40];
    __shared__ __align__(16) u16 Ba[64][40];
    __shared__ __align__(16) u16 Bb[64][40];
    int tid = threadIdx.x;
    int m0 = blockIdx.x * 128, n0 = blockIdx.y * 64;
    int wave = tid >> 6, lane = tid & 63;
    int wm = (wave >> 1) * 64, wn = (wave & 1) * 32;
    int q = lane >> 4, ln = lane & 15;
    f32x4 zero = {0.f, 0.f, 0.f, 0.f};
    f32x4 accA[4][2], accB[4][2];
#pragma unroll
    for (int i = 0; i < 4; ++i)
#pragma unroll
        for (int j = 0; j < 2; ++j) { accA[i][j] = zero; accB[i][j] = zero; }
    int sr = tid >> 1, sc = (tid & 1) * 16;
    const u16* Ap = A + (size_t)(m0 + sr) * 128 + sc;
    const u16* BpA = f1T_l + (size_t)(n0 + sr) * 128 + sc;
    const u16* BpB = f1T_l + (size_t)(512 + n0 + (sr - 64)) * 128 + sc;
#pragma unroll
    for (int k0 = 0; k0 < 128; k0 += 32) {
        uint4 a0 = *(const uint4*)(Ap + k0);
        uint4 a1 = *(const uint4*)(Ap + k0 + 8);
        *(uint4*)&As[sr][sc] = a0; *(uint4*)&As[sr][sc + 8] = a1;
        if (sr < 64) {
            uint4 w0 = *(const uint4*)(BpA + k0);
            uint4 w1 = *(const uint4*)(BpA + k0 + 8);
            *(uint4*)&Ba[sr][sc] = w0; *(uint4*)&Ba[sr][sc + 8] = w1;
        } else {
            uint4 w0 = *(const uint4*)(BpB + k0);
            uint4 w1 = *(const uint4*)(BpB + k0 + 8);
            *(uint4*)&Bb[sr - 64][sc] = w0; *(uint4*)&Bb[sr - 64][sc + 8] = w1;
        }
        __syncthreads();
        short8 af[4], ba[2], bb[2];
#pragma unroll
        for (int t = 0; t < 4; ++t) af[t] = *(const short8*)&As[wm + t * 16 + ln][q * 8];
#pragma unroll
        for (int t = 0; t < 2; ++t) {
            ba[t] = *(const short8*)&Ba[wn + t * 16 + ln][q * 8];
            bb[t] = *(const short8*)&Bb[wn + t * 16 + ln][q * 8];
        }
#pragma unroll
        for (int ti = 0; ti < 4; ++ti)
#pragma unroll
            for (int tj = 0; tj < 2; ++tj) {
                accA[ti][tj] = __builtin_amdgcn_mfma_f32_16x16x32_bf16(
                    af[ti], ba[tj], accA[ti][tj], 0, 0, 0);
                accB[ti][tj] = __builtin_amdgcn_mfma_f32_16x16x32_bf16(
                    af[ti], bb[tj], accB[ti][tj], 0, 0, 0);
            }
        __syncthreads();
    }
    int bf = *flagp;
#pragma unroll
    for (int tj = 0; tj < 2; ++tj) {
        int n = n0 + wn + tj * 16 + ln;
        float biasA = ldin(braw, bOff + n, bf);
        float biasB = ldin(braw, bOff + 512 + n, bf);
#pragma unroll
        for (int ti = 0; ti < 4; ++ti)
#pragma unroll
            for (int r = 0; r < 4; ++r) {
                int m = m0 + wm + ti * 16 + q * 4 + r;
                float ua = accA[ti][tj][r] + biasA;
                float ub = accB[ti][tj][r] + biasB;
                Vout[(size_t)m * 512 + n] = f2bf(ua / (1.0f + __expf(-ub)));
            }
    }
}

// ========== attention v5: mask-compressed K, full-MFMA, 4 blocks/CU ==========
// Only unmasked keys (compressed index list kidxg) are processed: ~2x work cut.
// Tail padding handled by tmask (pad -> p=0). Bias bytes pre-scaled x4 for
// direct ds_bpermute addressing. Fixed-shift softmax; z in f32.
__global__ __launch_bounds__(256, 4) void attn_kernel(
    const u16* __restrict__ Qh, const u16* __restrict__ Kh,
    const u16* __restrict__ Vh, const unsigned char* __restrict__ binsc,
    const u16* __restrict__ kidxg, const int* __restrict__ nktp,
    const unsigned* __restrict__ tmaskp, const float* __restrict__ deL,
    const float* __restrict__ abL, u16* __restrict__ out) {
    // de-swizzle: heads of one (b,qq) share id%8 -> same XCD L2 for binsc
    int id = blockIdx.x;
    int c = id & 7, t5 = id >> 3;
    int nh = t5 & 7;
    int pair = ((t5 >> 3) << 3) | c;
    int b = pair >> 2, qq = pair & 3;

    __shared__ __align__(16) u16 KsF[8192];      // frag-major K, 16 KB
    __shared__ __align__(16) u16 VT[16 * 520];   // V^T rows 520 f16, 16.25 KB
    __shared__ __align__(16) u16 Pl[4 * 16 * 40];// per-wave P tile, 5 KB

    int tid = threadIdx.x;
    int nt = __builtin_amdgcn_readfirstlane(nktp[b]);
    int nkp = nt * 32;
    const u16* Kp = Kh + (size_t)(b * Nq) * Hq + nh * HDq;
    const u16* Vp = Vh + (size_t)(b * Nq) * Hq + nh * HDq;
    for (int r = tid; r < nkp; r += 256) {
        int row = kidxg[b * 512 + r];
        int kt = r >> 5, s = (r >> 4) & 1, lnr = r & 15;
        uint4 k0v = *(const uint4*)(Kp + (size_t)row * Hq);
        uint4 k1v = *(const uint4*)(Kp + (size_t)row * Hq + 8);
        *(uint4*)&KsF[kt * 512 + s * 256 + lnr * 8]       = k0v;  // d 0..7
        *(uint4*)&KsF[kt * 512 + s * 256 + 128 + lnr * 8] = k1v;  // d 8..15
        uint4 v0 = *(const uint4*)(Vp + (size_t)row * Hq);
        uint4 v1 = *(const uint4*)(Vp + (size_t)row * Hq + 8);
        u16 vv[16];
        *(uint4*)&vv[0] = v0; *(uint4*)&vv[8] = v1;
#pragma unroll
        for (int d = 0; d < 16; ++d) VT[d * 520 + r] = vv[d];
    }
    __syncthreads();

    int wave = tid >> 6, lane = tid & 63;
    int quad = lane >> 4, ln = lane & 15;
    int q0w = qq * 128 + wave * 32;

    float tblf = (lane < 50) ? deL[lane * NHq + nh] + abL[nh] : 0.0f;
    int tbli = __float_as_int(tblf);
    unsigned tl = tmaskp[b * 16 + nt - 1];

    // hoisted Q B-frags (quads 2,3 supply the zero d-padding)
    half8 qf[2];
#pragma unroll
    for (int t = 0; t < 2; ++t) {
        uint4 qv = {0, 0, 0, 0};
        if (quad < 2)
            qv = *(const uint4*)(Qh + (size_t)(b * Nq + q0w + t * 16 + ln) * Hq
                                 + nh * HDq + quad * 8);
        qf[t] = *(half8*)&qv;
    }

    f32x4 zero = {0.f, 0.f, 0.f, 0.f};
    f32x4 acc[2] = {zero, zero};
    float zp[2] = {0.f, 0.f};
    _Float16* Pw = (_Float16*)&Pl[wave * 640];
    const _Float16* KsH = (const _Float16*)KsF;
    const _Float16* VTH = (const _Float16*)VT;
    const unsigned char* brow0 = binsc + ((size_t)b * 512 + (q0w + ln)) * 512;
    const unsigned char* brow1 = brow0 + (size_t)16 * 512;

    // prefetch kt=0 bias-byte dwords
    unsigned pb00 = *(const unsigned*)(brow0 + quad * 4);
    unsigned pb01 = *(const unsigned*)(brow0 + 16 + quad * 4);
    unsigned pb10 = *(const unsigned*)(brow1 + quad * 4);
    unsigned pb11 = *(const unsigned*)(brow1 + 16 + quad * 4);

    for (int kt = 0; kt < nt; ++kt) {
        int k0 = kt * 32;
        unsigned w = (kt == nt - 1) ? tl : 0u;
        unsigned cb00 = pb00, cb01 = pb01, cb10 = pb10, cb11 = pb11;
        if (kt < nt - 1) {
            pb00 = *(const unsigned*)(brow0 + k0 + 32 + quad * 4);
            pb01 = *(const unsigned*)(brow0 + k0 + 48 + quad * 4);
            pb10 = *(const unsigned*)(brow1 + k0 + 32 + quad * 4);
            pb11 = *(const unsigned*)(brow1 + k0 + 48 + quad * 4);
        }
        half8 vb = *(const half8*)(VTH + ln * 520 + k0 + quad * 8);
        half8 ka0 = {}, ka1 = {};
        if (quad < 2) {
            ka0 = *(const half8*)(KsH + kt * 512 + quad * 128 + ln * 8);
            ka1 = *(const half8*)(KsH + kt * 512 + 256 + quad * 128 + ln * 8);
        }
#pragma unroll
        for (int t = 0; t < 2; ++t) {
            unsigned bw0 = t == 0 ? cb00 : cb10;
            unsigned bw1 = t == 0 ? cb01 : cb11;
            f32x4 s0 = __builtin_amdgcn_mfma_f32_16x16x32_f16(ka0, qf[t], zero, 0, 0, 0);
            f32x4 s1 = __builtin_amdgcn_mfma_f32_16x16x32_f16(ka1, qf[t], zero, 0, 0, 0);
            float p[8];
#pragma unroll
            for (int r = 0; r < 4; ++r) {
                float bias = __int_as_float(__builtin_amdgcn_ds_bpermute(
                    (int)((bw0 >> (8 * r)) & 0xFFu), tbli));
                float sc = s0[r] + bias;
                bool m = (w >> (quad * 4 + r)) & 1u;
                p[r] = m ? 0.0f : __expf(sc);
            }
#pragma unroll
            for (int r = 0; r < 4; ++r) {
                float bias = __int_as_float(__builtin_amdgcn_ds_bpermute(
                    (int)((bw1 >> (8 * r)) & 0xFFu), tbli));
                float sc = s1[r] + bias;
                bool m = (w >> (16 + quad * 4 + r)) & 1u;
                p[4 + r] = m ? 0.0f : __expf(sc);
            }
            zp[t] += ((p[0] + p[1]) + (p[2] + p[3])) +
                     ((p[4] + p[5]) + (p[6] + p[7]));
            uint2 w0, w1;
            w0.x = pk2h(p[0], p[1]); w0.y = pk2h(p[2], p[3]);
            w1.x = pk2h(p[4], p[5]); w1.y = pk2h(p[6], p[7]);
            *(uint2*)(Pw + ln * 40 + quad * 4)      = w0;   // k = quad*4+r
            *(uint2*)(Pw + ln * 40 + 16 + quad * 4) = w1;   // k = 16+quad*4+r
            half8 pa = *(const half8*)(Pw + ln * 40 + quad * 8); // A[m=ln][k=quad*8+j]
            acc[t] = __builtin_amdgcn_mfma_f32_16x16x32_f16(pa, vb, acc[t], 0, 0, 0);
        }
    }
#pragma unroll
    for (int t = 0; t < 2; ++t) {
        zp[t] += __shfl_xor(zp[t], 16);
        zp[t] += __shfl_xor(zp[t], 32);
    }
#pragma unroll
    for (int t = 0; t < 2; ++t) {
#pragma unroll
        for (int r = 0; r < 4; ++r) {
            float zz = __shfl(zp[t], quad * 4 + r);
            float val = acc[t][r] / fmaxf(zz, 1e-35f);
            int qrow = q0w + t * 16 + quad * 4 + r;
            out[(size_t)(b * Nq + qrow) * Hq + nh * HDq + ln] = f2bf(val);
        }
    }
}

extern "C" void kernel_launch(void* const* d_in, const int* in_sizes, int n_in,
                              void* d_out, int out_size, void* d_ws, size_t ws_size,
                              hipStream_t stream) {
    const void* x  = d_in[0];
    const void* dist = d_in[1];
    const void* mask = d_in[2];
    const void* Wq = d_in[3];  const void* bq = d_in[4];
    const void* Wk = d_in[5];  const void* bk = d_in[6];
    const void* Wv = d_in[7];  const void* bv = d_in[8];
    const void* Wo = d_in[9];  const void* bo = d_in[10];
    const void* de = d_in[11]; const void* ab = d_in[12];
    const void* g1 = d_in[13]; const void* b1 = d_in[14];
    const void* g2 = d_in[15]; const void* b2 = d_in[16];
    const void* Wf1 = d_in[17]; const void* bf1 = d_in[18];
    const void* Wf2 = d_in[19]; const void* bf2 = d_in[20];

    char* ws = (char*)d_ws;
    const size_t OFF_DE   = 64;
    const size_t OFF_AB   = 5120;
    const size_t OFF_BINS = 8192;                    // binsc 8,388,608
    const size_t OFF_MSK  = OFF_BINS + 8388608;      // mbits 2 KB (4096 res)
    const size_t OFF_KIDX = OFF_MSK + 4096;          // 32768
    const size_t OFF_NKT  = OFF_KIDX + 32768;        // 256
    const size_t OFF_TM   = OFF_NKT + 256;           // 2048
    const size_t OFF_H    = OFF_TM + 4096;           // f32 8,388,608
    const size_t OFF_QKV  = OFF_H + 8388608;         // Qh,Kh,Vh f16 | vglu u16 16MB
    const size_t OFF_HN   = OFF_QKV + 25165824;      // u16 4,194,304
    const size_t OFF_ATT  = OFF_HN + 4194304;        // u16 4,194,304
    const size_t OFF_WT   = OFF_ATT + 4194304;       // u16 1,572,864
    const size_t NEEDED   = OFF_WT + 1572864;
    if (ws_size < NEEDED) return;

    int* flag = (int*)ws;
    float* deF = (float*)(ws + OFF_DE);
    float* abF = (float*)(ws + OFF_AB);
    unsigned char* binsc = (unsigned char*)(ws + OFF_BINS);
    unsigned* mbits = (unsigned*)(ws + OFF_MSK);
    u16* kidxg = (u16*)(ws + OFF_KIDX);
    int* nkt = (int*)(ws + OFF_NKT);
    unsigned* tmask = (unsigned*)(ws + OFF_TM);
    float* h = (float*)(ws + OFF_H);
    u16* Qh = (u16*)(ws + OFF_QKV);
    u16* Kh = Qh + 2097152;
    u16* Vh = Qh + 2 * 2097152;
    u16* vglu = (u16*)(ws + OFF_QKV);
    u16* hn = (u16*)(ws + OFF_HN);
    u16* att = (u16*)(ws + OFF_ATT);
    u16* qkvT = (u16*)(ws + OFF_WT);
    u16* oT  = qkvT + 147456;
    u16* f1T = oT + 49152;
    u16* f2T = f1T + 393216;

    prep_kernel<<<1, 256, 0, stream>>>(x, de, ab, mask, flag, deF, abF, mbits, Bq * Nq);
    kprep_kernel<<<32, 64, 0, stream>>>(mbits, kidxg, nkt, tmask);
    dim3 gbc(64, 32);
    binsc_kernel<<<gbc, 256, 0, stream>>>(dist, kidxg, nkt, binsc, flag);
    init_ln_kernel<<<4096, 256, 0, stream>>>(x, h, hn, g1, b1, flag);
    wtrans_kernel<<<768, 256, 0, stream>>>(Wq, Wk, Wv, Wo, Wf1, Wf2,
                                           qkvT, oT, f1T, f2T, flag);

    dim3 gqkv(256, 3);
    dim3 gglu(128, 8);
    for (int l = 0; l < 3; ++l) {
        qkv_mfma_kernel<<<gqkv, 256, 0, stream>>>(hn, qkvT + (size_t)l * 49152,
                                                  bq, bk, bv, (long)l * Hq,
                                                  Qh, Kh, Vh, flag);
        attn_kernel<<<1024, 256, 0, stream>>>(Qh, Kh, Vh, binsc, kidxg, nkt, tmask,
                                              deF + (long)l * 400, abF + (long)l * 8, att);
        // o-proj + residual + fused LN2 -> h, hn
        mfma_gemm64_kernel<<<256, 256, 0, stream>>>(att, oT + (size_t)l * 16384,
                                                    bo, (long)l * Hq, h, 128, 1, flag,
                                                    g2, b2, (long)l * Hq, hn, nullptr);
        glu_mfma_kernel<<<gglu, 256, 0, stream>>>(hn, f1T + (size_t)l * 131072,
                                                  bf1, (long)l * 1024, vglu, flag);
        if (l < 2) {
            // ff2 + residual + fused LN1 of next layer -> h, hn
            mfma_gemm64_kernel<<<256, 256, 0, stream>>>(vglu, f2T + (size_t)l * 65536,
                                                        bf2, (long)l * Hq, h, 512, 1, flag,
                                                        g1, b1, (long)(l + 1) * Hq, hn,
                                                        nullptr);
        } else {
            // last ff2: + residual, write final output
            mfma_gemm64_kernel<<<256, 256, 0, stream>>>(vglu, f2T + (size_t)l * 65536,
                                                        bf2, (long)l * Hq, h, 512, 1, flag,
                                                        nullptr, nullptr, 0, nullptr,
                                                        d_out);
        }
    }
}